// Round 3
// baseline (460.611 us; speedup 1.0000x reference)
//
#include <hip/hip_runtime.h>
#include <math.h>

#define L_  50
#define T_  100
#define NEG_INF_ -9000000000000000.0f

using bf16x8 = __attribute__((ext_vector_type(8))) short;
using f32x4 = __attribute__((ext_vector_type(4))) float;

__device__ __forceinline__ short f2bf(float f) {  // RNE fp32 -> bf16 bits
    unsigned u = __float_as_uint(f);
    return (short)((u + 0x7fffu + ((u >> 16) & 1u)) >> 16);
}
__device__ __forceinline__ unsigned short f2bfu(float f) {
    unsigned u = __float_as_uint(f);
    return (unsigned short)((u + 0x7fffu + ((u >> 16) & 1u)) >> 16);
}
__device__ __forceinline__ float bf2f(unsigned short u) {
    return __uint_as_float(((unsigned)u) << 16);
}
// packed RNE fp32x2 -> bf16x2 (single HW instr; same rounding as f2bf)
__device__ __forceinline__ unsigned cvt_pk_bf16(float lo, float hi) {
    unsigned r;
    asm("v_cvt_pk_bf16_f32 %0, %1, %2" : "=v"(r) : "v"(lo), "v"(hi));
    return r;
}
// tanh via exp+rcp: ~7 instr, |rel err| ~1e-7 (vs ~20-instr libm tanhf)
__device__ __forceinline__ float tanh_fast(float x) {
    const float cx = fminf(fmaxf(x, -15.f), 15.f);
    const float t = __expf(2.f * cx);
    return (t - 1.f) * __builtin_amdgcn_rcpf(t + 1.f);
}

// ---------------- pre-pass: W -> bf16 MFMA B-frags + user_com^T --------------
// mats 0,1 (W_att, W_out): 9 N-tiles; tile 8 = [W@a1 | W@a2 | 0...] (f1/f2 fold).
// mat 2 (att1_W): 8 N-tiles. Groups 104..135: ucT[g][k] = user_com[k][g] (f32).
// B-frag of mfma_f32_16x16x32_bf16: lane holds B[k = (lane>>4)*8 + j][n = lane&15].
extern "C" __global__ void __launch_bounds__(256) magnn_preswizzle(
    const float* __restrict__ W0, const float* __restrict__ W1,
    const float* __restrict__ W2, const float* __restrict__ a0,
    const float* __restrict__ a1v, const float* __restrict__ user_com,
    unsigned short* __restrict__ out, float* __restrict__ ucT) {
    const int t = blockIdx.x * 256 + threadIdx.x;  // 136 groups x 64 lanes
    const int gid = t >> 6, lane = t & 63;
    if (gid >= 136) return;
    if (gid >= 104) {  // user_com transpose: 32 groups x 4 float4/lane
        const int r = gid - 104;
#pragma unroll
        for (int rep = 0; rep < 4; ++rep) {
            const int c = r * 64 + lane + rep * 2048;  // chunk 0..8191
            const int g = c >> 6, k4 = (c & 63) << 2;
            float4 v;
            v.x = user_com[(size_t)(k4 + 0) * 128 + g];
            v.y = user_com[(size_t)(k4 + 1) * 128 + g];
            v.z = user_com[(size_t)(k4 + 2) * 128 + g];
            v.w = user_com[(size_t)(k4 + 3) * 128 + g];
            *(float4*)&ucT[(size_t)g * 256 + k4] = v;
        }
        return;
    }
    int mat, kt, nt;
    size_t base;
    if (gid < 72) {
        mat = gid / 36;
        const int rem = gid % 36;
        kt = rem / 9;
        nt = rem % 9;
        base = (size_t)mat * 18432 + (size_t)(((kt * 9 + nt) * 64 + lane) << 3);
    } else {
        mat = 2;
        const int rem = gid - 72;
        kt = rem >> 3;
        nt = rem & 7;
        base = 36864 + (size_t)(((kt * 8 + nt) * 64 + lane) << 3);
    }
    const float* Ws = (mat == 0) ? W0 : (mat == 1) ? W1 : W2;
    const int n = lane & 15;
    const int k0 = kt * 32 + (lane >> 4) * 8;
    bf16x8 v;
    if (nt < 8) {
        const int col = nt * 16 + n;
#pragma unroll
        for (int j = 0; j < 8; ++j) v[j] = f2bf(Ws[(size_t)(k0 + j) * 128 + col]);
    } else {
        // fold tile: 16 (j,vec) dots of len 128, parallel over 16 lanes of quad
        const float* avb = (mat == 0) ? a0 : a1v;
#pragma unroll
        for (int j = 0; j < 8; ++j) v[j] = 0;
#pragma unroll
        for (int pv = 0; pv < 16; ++pv) {
            const int j = pv & 7, vec = pv >> 3;
            const float* wr = Ws + (size_t)(k0 + j) * 128 + n * 8;
            const float* av = avb + vec * 128 + n * 8;
            float s = 0.f;
#pragma unroll
            for (int g = 0; g < 8; ++g) s = fmaf(wr[g], av[g], s);
            s += __shfl_xor(s, 1, 16);
            s += __shfl_xor(s, 2, 16);
            s += __shfl_xor(s, 4, 16);
            s += __shfl_xor(s, 8, 16);
            if (n == vec) v[j] = f2bf(s);
        }
    }
    *(bf16x8*)(out + base) = v;
}

// ---------------- MFMA gemm (GAT): ht^T = xb(50x128 bf16) @ W, + f1/f2 fold --
// Wave w owns output rows w*16..w*16+15 (rows>=50 computed from clamped row 49,
// stored as finite junk into ht rows 50..63 -- harmless, multiplied by P=0).
// ht layout: ht[col][row] (col-major) so P@h B-frags are contiguous.
__device__ __forceinline__ void gemm50_gat(
    const unsigned short* __restrict__ Wb,
    const unsigned short (&xb)[50][136], unsigned short (&ht)[128][72],
    float* __restrict__ f1s, float* __restrict__ f2s, int w, int lane) {
    const int n = lane & 15, quad = lane >> 4;
    const int mrd = w * 16 + n;
    const int mr = (mrd < 50) ? mrd : 49;
    f32x4 acc[9];
#pragma unroll
    for (int nt = 0; nt < 9; ++nt) acc[nt] = (f32x4){0.f, 0.f, 0.f, 0.f};

#pragma unroll
    for (int kt = 0; kt < 4; ++kt) {
        const bf16x8 af = *(const bf16x8*)&xb[mr][kt * 32 + quad * 8];
        const unsigned short* bp = Wb + (((kt * 9) * 64 + lane) << 3);
#pragma unroll
        for (int nt = 0; nt < 9; ++nt) {
            const bf16x8 bfr = *(const bf16x8*)(bp + (nt << 9));
            acc[nt] = __builtin_amdgcn_mfma_f32_16x16x32_bf16(af, bfr, acc[nt], 0, 0, 0);
        }
    }
    // C/D: col = lane&15 (+16*nt), row = w*16 + quad*4 + reg -> ht[col][row]
    const int rbase = w * 16 + quad * 4;
#pragma unroll
    for (int nt = 0; nt < 8; ++nt) {
        const int col = nt * 16 + n;
        uint2 pk;
        pk.x = cvt_pk_bf16(acc[nt][0], acc[nt][1]);
        pk.y = cvt_pk_bf16(acc[nt][2], acc[nt][3]);
        *(uint2*)&ht[col][rbase] = pk;  // 8B aligned (144B row stride)
    }
    if (n < 2) {
        float* fs = n ? f2s : f1s;  // fsc[128]: junk rows 50..63 land in-bounds
#pragma unroll
        for (int reg = 0; reg < 4; ++reg) fs[rbase + reg] = acc[8][reg];
    }
}

// ---------------- fused m1 + m2 + H-softmax ---------------------------------
// m1 = tanh(x @ att1_W + att1_b) stays in registers; m2 = m1 @ att2_W + att2_b
// accumulated per-lane, reduced over the 16 lanes of a quad (xor 1,2,4,8),
// softmaxed over H=4 and written straight to attn4.
__device__ __forceinline__ void gemm_m1_m2(
    const unsigned short* __restrict__ Wb, const float* __restrict__ att1_b,
    const float* __restrict__ att2_W, const float* __restrict__ att2_b,
    const unsigned short (&xb)[50][136], float* __restrict__ attn4,
    int w, int lane) {
    const int n = lane & 15, quad = lane >> 4;
    const int mrd = w * 16 + n;
    const int mr = (mrd < 50) ? mrd : 49;
    f32x4 acc[8];
#pragma unroll
    for (int nt = 0; nt < 8; ++nt) acc[nt] = (f32x4){0.f, 0.f, 0.f, 0.f};

#pragma unroll
    for (int kt = 0; kt < 4; ++kt) {
        const bf16x8 af = *(const bf16x8*)&xb[mr][kt * 32 + quad * 8];
        const unsigned short* bp = Wb + (((kt * 8) * 64 + lane) << 3);
#pragma unroll
        for (int nt = 0; nt < 8; ++nt) {
            const bf16x8 bfr = *(const bf16x8*)(bp + (nt << 9));
            acc[nt] = __builtin_amdgcn_mfma_f32_16x16x32_bf16(af, bfr, acc[nt], 0, 0, 0);
        }
    }

    float pm[4][4];  // [reg][h] partial m2, static-indexed (stays in VGPRs)
#pragma unroll
    for (int r = 0; r < 4; ++r)
#pragma unroll
        for (int h = 0; h < 4; ++h) pm[r][h] = 0.f;

#pragma unroll
    for (int nt = 0; nt < 8; ++nt) {
        const int col = nt * 16 + n;
        const float bv = att1_b[col];                       // L1-hot
        const float4 a4 = *(const float4*)&att2_W[col * 4]; // L1-hot
#pragma unroll
        for (int r = 0; r < 4; ++r) {
            const float tv = tanh_fast(acc[nt][r] + bv);
            pm[r][0] = fmaf(tv, a4.x, pm[r][0]);
            pm[r][1] = fmaf(tv, a4.y, pm[r][1]);
            pm[r][2] = fmaf(tv, a4.z, pm[r][2]);
            pm[r][3] = fmaf(tv, a4.w, pm[r][3]);
        }
    }
    // reduce across the 16 lanes of this quad (cols n,16+n,...,112+n cover all 128)
#pragma unroll
    for (int r = 0; r < 4; ++r)
#pragma unroll
        for (int h = 0; h < 4; ++h) {
            float v = pm[r][h];
            v += __shfl_xor(v, 1, 64);
            v += __shfl_xor(v, 2, 64);
            v += __shfl_xor(v, 4, 64);
            v += __shfl_xor(v, 8, 64);
            pm[r][h] = v;
        }
    if (n == 0) {
        const float ab0 = att2_b[0], ab1 = att2_b[1], ab2 = att2_b[2], ab3 = att2_b[3];
        const int rbase = w * 16 + quad * 4;
#pragma unroll
        for (int r = 0; r < 4; ++r) {
            const int row = rbase + r;
            if (row < L_) {
                const float m0 = pm[r][0] + ab0, m1 = pm[r][1] + ab1;
                const float m2 = pm[r][2] + ab2, m3 = pm[r][3] + ab3;
                const float mx = fmaxf(fmaxf(m0, m1), fmaxf(m2, m3));
                const float e0 = __expf(m0 - mx), e1 = __expf(m1 - mx);
                const float e2 = __expf(m2 - mx), e3 = __expf(m3 - mx);
                const float inv = 1.f / (e0 + e1 + e2 + e3);
                *(float4*)&attn4[row * 4] =
                    make_float4(e0 * inv, e1 * inv, e2 * inv, e3 * inv);
            }
        }
    }
}

extern "C" __global__ void __launch_bounds__(256, 4) magnn_fused(
    const int* __restrict__ iseq, const int* __restrict__ uids,
    const int* __restrict__ itp, const int* __restrict__ A,
    const float* __restrict__ item_emb, const float* __restrict__ user_emb,
    const float* __restrict__ W2t, const float* __restrict__ b2t,
    const float* __restrict__ att1_b, const float* __restrict__ att2_W,
    const float* __restrict__ att2_b, const unsigned short* __restrict__ Wb,
    const float* __restrict__ ucT, float* __restrict__ out) {
    // LDS: xb 13600 + ht 18432 + Pb 7200 + fsc 512 = 39744 B -> 4 blocks/CU.
    // Strides 136/72 ushorts (272/144 B): 16B-aligned b128 frags, <=2-way banks.
    __shared__ __align__(16) unsigned short xb[50][136];  // x, bf16 row-major
    __shared__ __align__(16) unsigned short ht[128][72];  // h^T, bf16 col-major
    __shared__ __align__(16) unsigned short Pb[50][72];   // E (unnorm attn), bf16
    __shared__ __align__(16) float fsc[128];
    float* f1s = fsc;
    float* f2s = fsc + 64;
    float* S = (float*)&Pb[0][0];  // Pb dead after GAT layers (barrier-protected):
    float* attn4 = S;              // [200] 50 x float4
    float* cat = S + 256;          // [256]
    float* vvec = S + 512;         // [128]

    const int tid = threadIdx.x;
    const int b = blockIdx.x;
    const int w = tid >> 6, lane = tid & 63;
    const int n16 = lane & 15, quad = lane >> 4;

    // ---- preload A rows as 16-bit mask; WAVE-LOCAL rows l = w*16+k ----------
    // (layer-invariant; wave w owns softmax rows w*16..w*16+15 -> PV needs no
    //  cross-wave barrier after the E-phase writes)
    const int* Ab = A + (size_t)b * (L_ * L_);
    unsigned amask = 0;
    if (lane < L_) {
#pragma unroll
        for (int k = 0; k < 16; ++k) {
            const int l = w * 16 + k;
            if (l < L_) amask |= (Ab[l * L_ + lane] > 0) ? (1u << k) : 0u;
        }
    }

    // ---- gather item embeddings -> xb (bf16); sval exact fp32 from global ----
    const int* isq = iseq + b * L_;
    for (int i = tid; i < L_ * 32; i += 256) {
        const int l = i >> 5, c4 = (i & 31) << 2;
        const float4 v = *(const float4*)&item_emb[(size_t)isq[l] * 128 + c4];
        uint2 pk;
        pk.x = cvt_pk_bf16(v.x, v.y);
        pk.y = cvt_pk_bf16(v.z, v.w);
        *(uint2*)&xb[l][c4] = pk;
    }
    float sval = 0.f;
    if (tid < 128) {
#pragma unroll 10
        for (int l = 0; l < L_; ++l)
            sval += item_emb[(size_t)isq[l] * 128 + tid];  // L1/L2-hot re-read
    }
    __syncthreads();  // B0

    // ---- 2 GAT layers: 2 barriers each (gemm->E, PV->next) ----
#pragma unroll 1
    for (int layer = 0; layer < 2; ++layer) {
        gemm50_gat(Wb + layer * 18432, xb, ht, f1s, f2s, w, lane);
        __syncthreads();  // B1: ht + f1/f2 visible to all waves
        // E = exp(tanh(f1+f2)) masked (bounded => no max shift; identical to
        // ref's max-subtracted softmax). Wave-local rows; sum folded into PV.
        {
            const float f2v = (lane < L_) ? f2s[lane] : 0.f;
#pragma unroll
            for (int k = 0; k < 16; ++k) {
                const int l = w * 16 + k;
                if (l < L_) {
                    const float e = tanh_fast(f1s[l] + f2v);
                    const float p = ((amask >> k) & 1u) ? __expf(e) : 0.f;
                    Pb[l][lane] = f2bfu(p);  // masked/junk lanes: exact 0
                }
            }
        }
        // NO barrier: PV reads only this wave's Pb rows (lgkmcnt ordering)
        {
            const int pm = w * 16 + n16;
            const int pmc = (pm < 50) ? pm : 49;
            const bf16x8 pa0 = *(const bf16x8*)&Pb[pmc][quad * 8];
            const bf16x8 pa1 = *(const bf16x8*)&Pb[pmc][32 + quad * 8];
            // ones-column B-frag: col 0 = 1.0 for all k (E cols >=50 are 0)
            bf16x8 bones;
#pragma unroll
            for (int j = 0; j < 8; ++j)
                bones[j] = (n16 == 0) ? (short)0x3F80 : (short)0;
            f32x4 sacc = (f32x4){0.f, 0.f, 0.f, 0.f};
            sacc = __builtin_amdgcn_mfma_f32_16x16x32_bf16(pa0, bones, sacc, 0, 0, 0);
            sacc = __builtin_amdgcn_mfma_f32_16x16x32_bf16(pa1, bones, sacc, 0, 0, 0);
            f32x4 oacc[8];
#pragma unroll
            for (int nt = 0; nt < 8; ++nt) oacc[nt] = (f32x4){0.f, 0.f, 0.f, 0.f};
#pragma unroll
            for (int nt = 0; nt < 8; ++nt) {
                const bf16x8 h0 = *(const bf16x8*)&ht[nt * 16 + n16][quad * 8];
                oacc[nt] = __builtin_amdgcn_mfma_f32_16x16x32_bf16(pa0, h0, oacc[nt], 0, 0, 0);
            }
#pragma unroll
            for (int nt = 0; nt < 8; ++nt) {
                const bf16x8 h1 = *(const bf16x8*)&ht[nt * 16 + n16][32 + quad * 8];
                oacc[nt] = __builtin_amdgcn_mfma_f32_16x16x32_bf16(pa1, h1, oacc[nt], 0, 0, 0);
            }
            // row sums live in lane quad*16 (col 0), element reg; broadcast + rcp
            float rinv[4];
#pragma unroll
            for (int reg = 0; reg < 4; ++reg) {
                const float s = __shfl(sacc[reg], (lane & 48), 64);
                rinv[reg] = __builtin_amdgcn_rcpf(s);
            }
            const int rb = w * 16 + quad * 4;
#pragma unroll
            for (int nt = 0; nt < 8; ++nt) {
                float ev[4];
#pragma unroll
                for (int reg = 0; reg < 4; ++reg) {
                    const float e = oacc[nt][reg] * rinv[reg];
                    ev[reg] = (e > 0.f) ? e : (__expf(e) - 1.f);
                }
                const unsigned q0 = cvt_pk_bf16(ev[0], ev[1]);
                const unsigned q1 = cvt_pk_bf16(ev[2], ev[3]);
                const int c = nt * 16 + n16;
                if (rb + 0 < L_) xb[rb + 0][c] = (unsigned short)(q0 & 0xffffu);
                if (rb + 1 < L_) xb[rb + 1][c] = (unsigned short)(q0 >> 16);
                if (rb + 2 < L_) xb[rb + 2][c] = (unsigned short)(q1 & 0xffffu);
                if (rb + 3 < L_) xb[rb + 3][c] = (unsigned short)(q1 >> 16);
            }
        }
        __syncthreads();  // B2: xb/ht handoff to next phase
    }

    // ---- m1+m2+softmax fused in registers -> attn4 (Pb region now dead) ----
    gemm_m1_m2(Wb + 36864, att1_b, att2_W, att2_b, xb, attn4, w, lane);
    __syncthreads();  // B3: attn4 visible

    // ---- matrix_z (tid<128, full L) -> cat[0:128]; user_emb -> cat[128:256] --
    if (tid < 128) {
        const int d = tid;
        float z0 = 0.f, z1 = 0.f, z2 = 0.f, z3 = 0.f;
#pragma unroll 5
        for (int l = 0; l < L_; ++l) {
            const float xv = bf2f(xb[l][d]);
            const float4 at = *(const float4*)&attn4[l * 4];  // broadcast
            z0 = fmaf(xv, at.x, z0);
            z1 = fmaf(xv, at.y, z1);
            z2 = fmaf(xv, at.z, z2);
            z3 = fmaf(xv, at.w, z3);
        }
        cat[d] = 0.25f * (tanh_fast(z0) + tanh_fast(z1) +
                          tanh_fast(z2) + tanh_fast(z3));
    } else {
        cat[tid] = user_emb[(size_t)uids[b] * 128 + (tid - 128)];
    }
    __syncthreads();  // B4

    // ---- fusion: vvec[g] = cat(256) . ucT[g] + sval (full dot, tid<128) ----
    if (tid < 128) {
        const float* ur = ucT + (size_t)tid * 256;
        float acc = 0.f;
#pragma unroll
        for (int k4 = 0; k4 < 64; ++k4) {
            const float4 cv = *(const float4*)&cat[k4 * 4];  // LDS broadcast
            const float4 uv = *(const float4*)&ur[k4 * 4];   // contiguous f32x4
            acc = fmaf(cv.x, uv.x, acc);
            acc = fmaf(cv.y, uv.y, acc);
            acc = fmaf(cv.z, uv.z, acc);
            acc = fmaf(cv.w, uv.w, acc);
        }
        vvec[tid] = acc + sval;
    }
    __syncthreads();  // B5

    // ---- out[b,t] = w2[t]·v + b2[t]; one t per 16-lane quad group ----
    // lane n16 holds v[n16*8..n16*8+7]; reduction = 4 intra-quad shuffles.
    {
        const float4 vva = *(const float4*)&vvec[n16 * 8];
        const float4 vvb = *(const float4*)&vvec[n16 * 8 + 4];
        const int* itpb = itp + b * T_;
        const int tq = w * 4 + quad;  // 0..15
        int ti[7];
        float bv[7];
#pragma unroll
        for (int i = 0; i < 7; ++i) {
            const int t = i * 16 + tq;
            ti[i] = itpb[(t < T_) ? t : 0];
        }
#pragma unroll
        for (int i = 0; i < 7; ++i) bv[i] = b2t[ti[i]];
#pragma unroll
        for (int i = 0; i < 7; ++i) {
            const int t = i * 16 + tq;
            const float* wr = W2t + (size_t)ti[i] * 128 + n16 * 8;
            const float4 wa = *(const float4*)wr;
            const float4 wb = *(const float4*)(wr + 4);
            float r = wa.x * vva.x;
            r = fmaf(wa.y, vva.y, r);
            r = fmaf(wa.z, vva.z, r);
            r = fmaf(wa.w, vva.w, r);
            r = fmaf(wb.x, vvb.x, r);
            r = fmaf(wb.y, vvb.y, r);
            r = fmaf(wb.z, vvb.z, r);
            r = fmaf(wb.w, vvb.w, r);
            r += __shfl_xor(r, 1, 64);
            r += __shfl_xor(r, 2, 64);
            r += __shfl_xor(r, 4, 64);
            r += __shfl_xor(r, 8, 64);
            if (n16 == 0 && t < T_) out[b * T_ + t] = r + bv[i];
        }
    }
}

extern "C" void kernel_launch(void* const* d_in, const int* in_sizes, int n_in,
                              void* d_out, int out_size, void* d_ws, size_t ws_size,
                              hipStream_t stream) {
    const int* iseq = (const int*)d_in[0];
    const int* uids = (const int*)d_in[1];
    const int* itp = (const int*)d_in[2];
    const int* A = (const int*)d_in[3];
    const float* item_emb = (const float*)d_in[4];
    const float* user_emb = (const float*)d_in[5];
    const float* W2t = (const float*)d_in[6];
    const float* b2t = (const float*)d_in[7];
    const float* W_att = (const float*)d_in[8];
    const float* a_att = (const float*)d_in[9];
    const float* W_out = (const float*)d_in[10];
    const float* a_out = (const float*)d_in[11];
    const float* att1_W = (const float*)d_in[12];
    const float* att1_b = (const float*)d_in[13];
    const float* att2_W = (const float*)d_in[14];
    const float* att2_b = (const float*)d_in[15];
    const float* user_com = (const float*)d_in[16];
    float* out = (float*)d_out;
    unsigned short* Wb = (unsigned short*)d_ws;  // 53248 bf16 = 104 KiB
    float* ucT = (float*)((char*)d_ws + 106496);  // 128x256 f32 = 128 KiB

    magnn_preswizzle<<<dim3(34), dim3(256), 0, stream>>>(
        W_att, W_out, att1_W, a_att, a_out, user_com, Wb, ucT);

    const int B = in_sizes[1];  // user_ids is (B,)
    magnn_fused<<<dim3(B), dim3(256), 0, stream>>>(
        iseq, uids, itp, A, item_emb, user_emb, W2t, b2t, att1_b, att2_W,
        att2_b, Wb, ucT, out);
}

// Round 4
// 409.140 us; speedup vs baseline: 1.1258x; 1.1258x over previous
//
#include <hip/hip_runtime.h>
#include <math.h>

#define L_  50
#define T_  100
#define NEG_INF_ -9000000000000000.0f

using bf16x8 = __attribute__((ext_vector_type(8))) short;
using f32x4 = __attribute__((ext_vector_type(4))) float;

__device__ __forceinline__ short f2bf(float f) {  // RNE fp32 -> bf16 bits
    unsigned u = __float_as_uint(f);
    return (short)((u + 0x7fffu + ((u >> 16) & 1u)) >> 16);
}
__device__ __forceinline__ unsigned short f2bfu(float f) {
    unsigned u = __float_as_uint(f);
    return (unsigned short)((u + 0x7fffu + ((u >> 16) & 1u)) >> 16);
}
__device__ __forceinline__ float bf2f(unsigned short u) {
    return __uint_as_float(((unsigned)u) << 16);
}
// tanh via exp+rcp: ~7 instr, |rel err| ~1e-7 (vs ~20-instr libm tanhf)
__device__ __forceinline__ float tanh_fast(float x) {
    const float cx = fminf(fmaxf(x, -15.f), 15.f);
    const float t = __expf(2.f * cx);
    return (t - 1.f) * __builtin_amdgcn_rcpf(t + 1.f);
}

// ---------------- pre-pass: W -> bf16 MFMA B-frags ---------------------------
// mats 0,1 (W_att, W_out): 9 N-tiles; tile 8 = [W@a1 | W@a2 | 0...] (f1/f2 fold).
// mat 2 (att1_W): 8 N-tiles.
// B-frag of mfma_f32_16x16x32_bf16: lane holds B[k = (lane>>4)*8 + j][n = lane&15].
extern "C" __global__ void __launch_bounds__(256) magnn_preswizzle(
    const float* __restrict__ W0, const float* __restrict__ W1,
    const float* __restrict__ W2, const float* __restrict__ a0,
    const float* __restrict__ a1v, unsigned short* __restrict__ out) {
    const int t = blockIdx.x * 256 + threadIdx.x;  // 104 groups x 64 lanes
    const int gid = t >> 6, lane = t & 63;
    if (gid >= 104) return;
    int mat, kt, nt;
    size_t base;
    if (gid < 72) {
        mat = gid / 36;
        const int rem = gid % 36;
        kt = rem / 9;
        nt = rem % 9;
        base = (size_t)mat * 18432 + (size_t)(((kt * 9 + nt) * 64 + lane) << 3);
    } else {
        mat = 2;
        const int rem = gid - 72;
        kt = rem >> 3;
        nt = rem & 7;
        base = 36864 + (size_t)(((kt * 8 + nt) * 64 + lane) << 3);
    }
    const float* Ws = (mat == 0) ? W0 : (mat == 1) ? W1 : W2;
    const int n = lane & 15;
    const int k0 = kt * 32 + (lane >> 4) * 8;
    bf16x8 v;
    if (nt < 8) {
        const int col = nt * 16 + n;
#pragma unroll
        for (int j = 0; j < 8; ++j) v[j] = f2bf(Ws[(size_t)(k0 + j) * 128 + col]);
    } else {
        // fold tile: 16 (j,vec) dots of len 128, parallel over 16 lanes of quad
        const float* avb = (mat == 0) ? a0 : a1v;
#pragma unroll
        for (int j = 0; j < 8; ++j) v[j] = 0;
#pragma unroll
        for (int pv = 0; pv < 16; ++pv) {
            const int j = pv & 7, vec = pv >> 3;
            const float* wr = Ws + (size_t)(k0 + j) * 128 + n * 8;
            const float* av = avb + vec * 128 + n * 8;
            float s = 0.f;
#pragma unroll
            for (int g = 0; g < 8; ++g) s = fmaf(wr[g], av[g], s);
            s += __shfl_xor(s, 1, 16);
            s += __shfl_xor(s, 2, 16);
            s += __shfl_xor(s, 4, 16);
            s += __shfl_xor(s, 8, 16);
            if (n == vec) v[j] = f2bf(s);
        }
    }
    *(bf16x8*)(out + base) = v;
}

// ---------------- MFMA gemm (GAT): ht^T = xb(50x128 bf16) @ W, + f1/f2 fold --
// Wave w owns output rows w*16..w*16+15 (rows>=50 computed from clamped row 49,
// stored as finite junk into ht rows 50..63 -- harmless, multiplied by P=0).
// ht layout: ht[col][row] (col-major) so P@h B-frags are contiguous.
__device__ __forceinline__ void gemm50_gat(
    const unsigned short* __restrict__ Wb,
    const unsigned short (&xb)[50][136], unsigned short (&ht)[128][72],
    float* __restrict__ f1s, float* __restrict__ f2s, int w, int lane) {
    const int n = lane & 15, quad = lane >> 4;
    const int mrd = w * 16 + n;
    const int mr = (mrd < 50) ? mrd : 49;
    f32x4 acc[9];
#pragma unroll
    for (int nt = 0; nt < 9; ++nt) acc[nt] = (f32x4){0.f, 0.f, 0.f, 0.f};

#pragma unroll
    for (int kt = 0; kt < 4; ++kt) {
        const bf16x8 af = *(const bf16x8*)&xb[mr][kt * 32 + quad * 8];
        const unsigned short* bp = Wb + (((kt * 9) * 64 + lane) << 3);
#pragma unroll
        for (int nt = 0; nt < 9; ++nt) {
            const bf16x8 bfr = *(const bf16x8*)(bp + (nt << 9));
            acc[nt] = __builtin_amdgcn_mfma_f32_16x16x32_bf16(af, bfr, acc[nt], 0, 0, 0);
        }
    }
    // C/D: col = lane&15 (+16*nt), row = w*16 + quad*4 + reg -> ht[col][row]
    const int rbase = w * 16 + quad * 4;
#pragma unroll
    for (int nt = 0; nt < 8; ++nt) {
        const int col = nt * 16 + n;
        ushort4 pk;
        pk.x = f2bfu(acc[nt][0]);
        pk.y = f2bfu(acc[nt][1]);
        pk.z = f2bfu(acc[nt][2]);
        pk.w = f2bfu(acc[nt][3]);
        *(ushort4*)&ht[col][rbase] = pk;  // 8B aligned (144B row stride)
    }
    if (n < 2) {
        float* fs = n ? f2s : f1s;  // fsc[128]: junk rows 50..63 land in-bounds
#pragma unroll
        for (int reg = 0; reg < 4; ++reg) fs[rbase + reg] = acc[8][reg];
    }
}

// ---------------- fused m1 + m2 + H-softmax ---------------------------------
// m1 = tanh(x @ att1_W + att1_b) stays in registers; m2 = m1 @ att2_W + att2_b
// accumulated per-lane, reduced over the 16 lanes of a quad (xor 1,2,4,8),
// softmaxed over H=4 and written straight to attn4.
__device__ __forceinline__ void gemm_m1_m2(
    const unsigned short* __restrict__ Wb, const float* __restrict__ att1_b,
    const float* __restrict__ att2_W, const float* __restrict__ att2_b,
    const unsigned short (&xb)[50][136], float* __restrict__ attn4,
    int w, int lane) {
    const int n = lane & 15, quad = lane >> 4;
    const int mrd = w * 16 + n;
    const int mr = (mrd < 50) ? mrd : 49;
    f32x4 acc[8];
#pragma unroll
    for (int nt = 0; nt < 8; ++nt) acc[nt] = (f32x4){0.f, 0.f, 0.f, 0.f};

#pragma unroll
    for (int kt = 0; kt < 4; ++kt) {
        const bf16x8 af = *(const bf16x8*)&xb[mr][kt * 32 + quad * 8];
        const unsigned short* bp = Wb + (((kt * 8) * 64 + lane) << 3);
#pragma unroll
        for (int nt = 0; nt < 8; ++nt) {
            const bf16x8 bfr = *(const bf16x8*)(bp + (nt << 9));
            acc[nt] = __builtin_amdgcn_mfma_f32_16x16x32_bf16(af, bfr, acc[nt], 0, 0, 0);
        }
    }

    float pm[4][4];  // [reg][h] partial m2, static-indexed (stays in VGPRs)
#pragma unroll
    for (int r = 0; r < 4; ++r)
#pragma unroll
        for (int h = 0; h < 4; ++h) pm[r][h] = 0.f;

#pragma unroll
    for (int nt = 0; nt < 8; ++nt) {
        const int col = nt * 16 + n;
        const float bv = att1_b[col];                       // L1-hot
        const float4 a4 = *(const float4*)&att2_W[col * 4]; // L1-hot
#pragma unroll
        for (int r = 0; r < 4; ++r) {
            const float tv = tanh_fast(acc[nt][r] + bv);
            pm[r][0] = fmaf(tv, a4.x, pm[r][0]);
            pm[r][1] = fmaf(tv, a4.y, pm[r][1]);
            pm[r][2] = fmaf(tv, a4.z, pm[r][2]);
            pm[r][3] = fmaf(tv, a4.w, pm[r][3]);
        }
    }
    // reduce across the 16 lanes of this quad (cols n,16+n,...,112+n cover all 128)
#pragma unroll
    for (int r = 0; r < 4; ++r)
#pragma unroll
        for (int h = 0; h < 4; ++h) {
            float v = pm[r][h];
            v += __shfl_xor(v, 1, 64);
            v += __shfl_xor(v, 2, 64);
            v += __shfl_xor(v, 4, 64);
            v += __shfl_xor(v, 8, 64);
            pm[r][h] = v;
        }
    if (n == 0) {
        const float ab0 = att2_b[0], ab1 = att2_b[1], ab2 = att2_b[2], ab3 = att2_b[3];
        const int rbase = w * 16 + quad * 4;
#pragma unroll
        for (int r = 0; r < 4; ++r) {
            const int row = rbase + r;
            if (row < L_) {
                const float m0 = pm[r][0] + ab0, m1 = pm[r][1] + ab1;
                const float m2 = pm[r][2] + ab2, m3 = pm[r][3] + ab3;
                const float mx = fmaxf(fmaxf(m0, m1), fmaxf(m2, m3));
                const float e0 = __expf(m0 - mx), e1 = __expf(m1 - mx);
                const float e2 = __expf(m2 - mx), e3 = __expf(m3 - mx);
                const float inv = 1.f / (e0 + e1 + e2 + e3);
                *(float4*)&attn4[row * 4] =
                    make_float4(e0 * inv, e1 * inv, e2 * inv, e3 * inv);
            }
        }
    }
}

extern "C" __global__ void __launch_bounds__(256, 4) magnn_fused(
    const int* __restrict__ iseq, const int* __restrict__ uids,
    const int* __restrict__ itp, const int* __restrict__ A,
    const float* __restrict__ item_emb, const float* __restrict__ user_emb,
    const float* __restrict__ W2t, const float* __restrict__ b2t,
    const float* __restrict__ att1_b, const float* __restrict__ att2_W,
    const float* __restrict__ att2_b, const float* __restrict__ user_com,
    const unsigned short* __restrict__ Wb, float* __restrict__ out) {
    // LDS: xb 13600 + ht 18432 + Pb 7200 + fsc 512 + spart 512 = 40256 B
    // -> 4 blocks/CU (<= 40960). Strides 136/72 ushorts: 16B-aligned b128 frags.
    __shared__ __align__(16) unsigned short xb[50][136];  // x, bf16 row-major
    __shared__ __align__(16) unsigned short ht[128][72];  // h^T, bf16 col-major
    __shared__ __align__(16) unsigned short Pb[50][72];   // E (unnorm attn), bf16
    __shared__ __align__(16) float fsc[128];
    __shared__ __align__(16) float spart[128];            // sval partial (l>=25)
    float* f1s = fsc;
    float* f2s = fsc + 64;
    float* S = (float*)&Pb[0][0];  // Pb dead after GAT layers:
    float* attn4 = S;              // [200] 50 x float4
    float* cat = S + 256;          // [256]
    float* fpart = S + 512;        // [128]
    float* vvec = S + 640;         // [128]
    float* zpart = S + 768;        // [4][128]

    const int tid = threadIdx.x;
    const int b = blockIdx.x;
    const int w = tid >> 6, lane = tid & 63;
    const int n16 = lane & 15, quad = lane >> 4;

    // ---- preload A rows as 16-bit mask; WAVE-LOCAL rows l = w*16+k ----------
    // (layer-invariant; wave w owns E-rows w*16..w*16+15 -> the E->PV handoff
    //  is wave-private, so no barrier is needed between E and PV)
    const int* Ab = A + (size_t)b * (L_ * L_);
    unsigned amask = 0;
    if (lane < L_) {
#pragma unroll
        for (int k = 0; k < 16; ++k) {
            const int l = w * 16 + k;
            if (l < L_) amask |= (Ab[l * L_ + lane] > 0) ? (1u << k) : 0u;
        }
    }

    // ---- gather item embeddings -> xb (bf16); sval exact fp32, split halves --
    const int* isq = iseq + b * L_;
    for (int i = tid; i < L_ * 32; i += 256) {
        const int l = i >> 5, c4 = (i & 31) << 2;
        const float4 v = *(const float4*)&item_emb[(size_t)isq[l] * 128 + c4];
        ushort4 pk;
        pk.x = f2bfu(v.x); pk.y = f2bfu(v.y); pk.z = f2bfu(v.z); pk.w = f2bfu(v.w);
        *(ushort4*)&xb[l][c4] = pk;
    }
    float sval = 0.f;
    {
        const int d = tid & 127, hf2 = tid >> 7;
        const int l0 = hf2 * 25;
        float s = 0.f;
#pragma unroll 5
        for (int l = l0; l < l0 + 25; ++l)
            s += item_emb[(size_t)isq[l] * 128 + d];  // L1/L2-hot re-read
        if (hf2) spart[d] = s;
        else sval = s;
    }
    __syncthreads();  // B0

    // ---- 2 GAT layers: 2 barriers each ----
#pragma unroll 1
    for (int layer = 0; layer < 2; ++layer) {
        gemm50_gat(Wb + layer * 18432, xb, ht, f1s, f2s, w, lane);
        __syncthreads();  // B1: ht + f1/f2 visible to all waves
        // E = exp(tanh(f1+f2)) masked (bounded => no max shift; identical to
        // ref's max-subtracted softmax). Wave-local rows; sum folded into PV.
        {
            const float f2v = (lane < L_) ? f2s[lane] : 0.f;
#pragma unroll
            for (int k = 0; k < 16; ++k) {
                const int l = w * 16 + k;
                if (l < L_) {
                    const float e = tanh_fast(f1s[l] + f2v);
                    const float p = ((amask >> k) & 1u) ? __expf(e) : 0.f;
                    Pb[l][lane] = f2bfu(p);  // masked/junk lanes: exact 0
                }
            }
        }
        // NO barrier: PV reads only this wave's Pb rows (same-wave LDS order)
        {
            const int pm = w * 16 + n16;
            const int pmc = (pm < 50) ? pm : 49;
            const bf16x8 pa0 = *(const bf16x8*)&Pb[pmc][quad * 8];
            const bf16x8 pa1 = *(const bf16x8*)&Pb[pmc][32 + quad * 8];
            // ones-column B-frag: col 0 = 1.0 for all k (E cols >=50 are 0)
            bf16x8 bones;
#pragma unroll
            for (int j = 0; j < 8; ++j)
                bones[j] = (n16 == 0) ? (short)0x3F80 : (short)0;
            f32x4 sacc = (f32x4){0.f, 0.f, 0.f, 0.f};
            sacc = __builtin_amdgcn_mfma_f32_16x16x32_bf16(pa0, bones, sacc, 0, 0, 0);
            sacc = __builtin_amdgcn_mfma_f32_16x16x32_bf16(pa1, bones, sacc, 0, 0, 0);
            f32x4 oacc[8];
#pragma unroll
            for (int nt = 0; nt < 8; ++nt) oacc[nt] = (f32x4){0.f, 0.f, 0.f, 0.f};
#pragma unroll
            for (int nt = 0; nt < 8; ++nt) {
                const bf16x8 h0 = *(const bf16x8*)&ht[nt * 16 + n16][quad * 8];
                oacc[nt] = __builtin_amdgcn_mfma_f32_16x16x32_bf16(pa0, h0, oacc[nt], 0, 0, 0);
            }
#pragma unroll
            for (int nt = 0; nt < 8; ++nt) {
                const bf16x8 h1 = *(const bf16x8*)&ht[nt * 16 + n16][32 + quad * 8];
                oacc[nt] = __builtin_amdgcn_mfma_f32_16x16x32_bf16(pa1, h1, oacc[nt], 0, 0, 0);
            }
            // row sums live in lane quad*16 (col 0), element reg; broadcast + rcp
            float rinv[4];
#pragma unroll
            for (int reg = 0; reg < 4; ++reg) {
                const float s = __shfl(sacc[reg], (lane & 48), 64);
                rinv[reg] = __builtin_amdgcn_rcpf(s);
            }
            const int rb = w * 16 + quad * 4;
#pragma unroll
            for (int nt = 0; nt < 8; ++nt) {
#pragma unroll
                for (int reg = 0; reg < 4; ++reg) {
                    const int row = rb + reg;
                    if (row < L_) {
                        float e = oacc[nt][reg] * rinv[reg];
                        e = (e > 0.f) ? e : (__expf(e) - 1.f);
                        xb[row][nt * 16 + n16] = f2bfu(e);
                    }
                }
            }
        }
        __syncthreads();  // B2: xb/ht handoff to next phase
    }

    // ---- m1+m2+softmax fused in registers -> attn4 (Pb region now dead) ----
    gemm_m1_m2(Wb + 36864, att1_b, att2_W, att2_b, xb, attn4, w, lane);
    __syncthreads();  // B3: attn4 visible

    // ---- matrix_z with all 256 threads: halves of L, partials via LDS ----
    {
        const int d = tid & 127, hf2 = tid >> 7;
        float z0 = 0.f, z1 = 0.f, z2 = 0.f, z3 = 0.f;
        const int l0 = hf2 * 25;
#pragma unroll
        for (int li = 0; li < 25; ++li) {
            const int l = l0 + li;
            const float xv = bf2f(xb[l][d]);
            const float4 at = *(const float4*)&attn4[l * 4];  // broadcast
            z0 = fmaf(xv, at.x, z0);
            z1 = fmaf(xv, at.y, z1);
            z2 = fmaf(xv, at.z, z2);
            z3 = fmaf(xv, at.w, z3);
        }
        if (hf2) {
            zpart[0 * 128 + d] = z0;
            zpart[1 * 128 + d] = z1;
            zpart[2 * 128 + d] = z2;
            zpart[3 * 128 + d] = z3;
            cat[128 + d] = user_emb[(size_t)uids[b] * 128 + d];
        }
        __syncthreads();  // B4
        if (!hf2) {
            z0 += zpart[0 * 128 + d];
            z1 += zpart[1 * 128 + d];
            z2 += zpart[2 * 128 + d];
            z3 += zpart[3 * 128 + d];
            cat[d] = 0.25f * (tanh_fast(z0) + tanh_fast(z1) +
                              tanh_fast(z2) + tanh_fast(z3));
        }
        __syncthreads();  // B5
    }

    // ---- fusion = cat @ user_com (coalesced strided cols); v = fusion + s ----
    {
        const int g = tid & 127, hf = tid >> 7;
        const float* ucb = user_com + hf * 128 * 128 + g;
        const float* cc = cat + hf * 128;
        float acc = 0.f;
#pragma unroll 16
        for (int k = 0; k < 128; ++k) acc = fmaf(cc[k], ucb[(size_t)k * 128], acc);
        if (hf) fpart[g] = acc;
        __syncthreads();  // B6
        if (!hf) vvec[g] = acc + fpart[g] + sval + spart[g];
    }
    __syncthreads();  // B7

    // ---- out[b,t] = w2[t]·v + b2[t]; one t per 16-lane quad group ----
    // lane n16 holds v[n16*8..n16*8+7]; reduction = 4 intra-quad shuffles.
    {
        const float4 vva = *(const float4*)&vvec[n16 * 8];
        const float4 vvb = *(const float4*)&vvec[n16 * 8 + 4];
        const int* itpb = itp + b * T_;
        const int tq = w * 4 + quad;  // 0..15
        int ti[7];
        float bv[7];
#pragma unroll
        for (int i = 0; i < 7; ++i) {
            const int t = i * 16 + tq;
            ti[i] = itpb[(t < T_) ? t : 0];
        }
#pragma unroll
        for (int i = 0; i < 7; ++i) bv[i] = b2t[ti[i]];
#pragma unroll
        for (int i = 0; i < 7; ++i) {
            const int t = i * 16 + tq;
            const float* wr = W2t + (size_t)ti[i] * 128 + n16 * 8;
            const float4 wa = *(const float4*)wr;
            const float4 wb = *(const float4*)(wr + 4);
            float r = wa.x * vva.x;
            r = fmaf(wa.y, vva.y, r);
            r = fmaf(wa.z, vva.z, r);
            r = fmaf(wa.w, vva.w, r);
            r = fmaf(wb.x, vvb.x, r);
            r = fmaf(wb.y, vvb.y, r);
            r = fmaf(wb.z, vvb.z, r);
            r = fmaf(wb.w, vvb.w, r);
            r += __shfl_xor(r, 1, 64);
            r += __shfl_xor(r, 2, 64);
            r += __shfl_xor(r, 4, 64);
            r += __shfl_xor(r, 8, 64);
            if (n16 == 0 && t < T_) out[b * T_ + t] = r + bv[i];
        }
    }
}

extern "C" void kernel_launch(void* const* d_in, const int* in_sizes, int n_in,
                              void* d_out, int out_size, void* d_ws, size_t ws_size,
                              hipStream_t stream) {
    const int* iseq = (const int*)d_in[0];
    const int* uids = (const int*)d_in[1];
    const int* itp = (const int*)d_in[2];
    const int* A = (const int*)d_in[3];
    const float* item_emb = (const float*)d_in[4];
    const float* user_emb = (const float*)d_in[5];
    const float* W2t = (const float*)d_in[6];
    const float* b2t = (const float*)d_in[7];
    const float* W_att = (const float*)d_in[8];
    const float* a_att = (const float*)d_in[9];
    const float* W_out = (const float*)d_in[10];
    const float* a_out = (const float*)d_in[11];
    const float* att1_W = (const float*)d_in[12];
    const float* att1_b = (const float*)d_in[13];
    const float* att2_W = (const float*)d_in[14];
    const float* att2_b = (const float*)d_in[15];
    const float* user_com = (const float*)d_in[16];
    float* out = (float*)d_out;
    unsigned short* Wb = (unsigned short*)d_ws;  // 53248 bf16 = 104 KiB

    magnn_preswizzle<<<dim3(26), dim3(256), 0, stream>>>(W_att, W_out, att1_W,
                                                         a_att, a_out, Wb);

    const int B = in_sizes[1];  // user_ids is (B,)
    magnn_fused<<<dim3(B), dim3(256), 0, stream>>>(
        iseq, uids, itp, A, item_emb, user_emb, W2t, b2t, att1_b, att2_W,
        att2_b, user_com, Wb, out);
}

// Round 5
// 344.676 us; speedup vs baseline: 1.3364x; 1.1870x over previous
//
#include <hip/hip_runtime.h>
#include <math.h>

#define L_  50
#define T_  100
#define NEG_INF_ -9000000000000000.0f

using bf16x8 = __attribute__((ext_vector_type(8))) short;
using f32x4 = __attribute__((ext_vector_type(4))) float;

__device__ __forceinline__ short f2bf(float f) {  // RNE fp32 -> bf16 bits
    unsigned u = __float_as_uint(f);
    return (short)((u + 0x7fffu + ((u >> 16) & 1u)) >> 16);
}
__device__ __forceinline__ unsigned short f2bfu(float f) {
    unsigned u = __float_as_uint(f);
    return (unsigned short)((u + 0x7fffu + ((u >> 16) & 1u)) >> 16);
}
__device__ __forceinline__ float bf2f(unsigned short u) {
    return __uint_as_float(((unsigned)u) << 16);
}
// tanh via exp+rcp: ~7 instr, |rel err| ~1e-7 (vs ~20-instr libm tanhf)
__device__ __forceinline__ float tanh_fast(float x) {
    const float cx = fminf(fmaxf(x, -15.f), 15.f);
    const float t = __expf(2.f * cx);
    return (t - 1.f) * __builtin_amdgcn_rcpf(t + 1.f);
}

// ---------------- pre-pass: W -> bf16 MFMA B-frags ---------------------------
// mats 0,1 (W_att, W_out): 9 N-tiles; tile 8 = [W@a1 | W@a2 | 0...] (f1/f2 fold).
// mat 2 (att1_W): 8 N-tiles.
// B-frag of mfma_f32_16x16x32_bf16: lane holds B[k = (lane>>4)*8 + j][n = lane&15].
extern "C" __global__ void __launch_bounds__(256) magnn_preswizzle(
    const float* __restrict__ W0, const float* __restrict__ W1,
    const float* __restrict__ W2, const float* __restrict__ a0,
    const float* __restrict__ a1v, unsigned short* __restrict__ out) {
    const int t = blockIdx.x * 256 + threadIdx.x;  // 104 groups x 64 lanes
    const int gid = t >> 6, lane = t & 63;
    if (gid >= 104) return;
    int mat, kt, nt;
    size_t base;
    if (gid < 72) {
        mat = gid / 36;
        const int rem = gid % 36;
        kt = rem / 9;
        nt = rem % 9;
        base = (size_t)mat * 18432 + (size_t)(((kt * 9 + nt) * 64 + lane) << 3);
    } else {
        mat = 2;
        const int rem = gid - 72;
        kt = rem >> 3;
        nt = rem & 7;
        base = 36864 + (size_t)(((kt * 8 + nt) * 64 + lane) << 3);
    }
    const float* Ws = (mat == 0) ? W0 : (mat == 1) ? W1 : W2;
    const int n = lane & 15;
    const int k0 = kt * 32 + (lane >> 4) * 8;
    bf16x8 v;
    if (nt < 8) {
        const int col = nt * 16 + n;
#pragma unroll
        for (int j = 0; j < 8; ++j) v[j] = f2bf(Ws[(size_t)(k0 + j) * 128 + col]);
    } else {
        // fold tile: 16 (j,vec) dots of len 128, parallel over 16 lanes of quad
        const float* avb = (mat == 0) ? a0 : a1v;
#pragma unroll
        for (int j = 0; j < 8; ++j) v[j] = 0;
#pragma unroll
        for (int pv = 0; pv < 16; ++pv) {
            const int j = pv & 7, vec = pv >> 3;
            const float* wr = Ws + (size_t)(k0 + j) * 128 + n * 8;
            const float* av = avb + vec * 128 + n * 8;
            float s = 0.f;
#pragma unroll
            for (int g = 0; g < 8; ++g) s = fmaf(wr[g], av[g], s);
            s += __shfl_xor(s, 1, 16);
            s += __shfl_xor(s, 2, 16);
            s += __shfl_xor(s, 4, 16);
            s += __shfl_xor(s, 8, 16);
            if (n == vec) v[j] = f2bf(s);
        }
    }
    *(bf16x8*)(out + base) = v;
}

// ---------------- MFMA gemm (GAT): ht^T = xb(50x128 bf16) @ W, + f1/f2 fold --
// Wave w owns output rows w*16..w*16+15 (rows>=50 computed from clamped row 49,
// stored as finite junk into ht rows 50..63 -- harmless, multiplied by P=0).
// ht layout: ht[col][row] (col-major) so P@h B-frags are contiguous.
__device__ __forceinline__ void gemm50_gat(
    const unsigned short* __restrict__ Wb,
    const unsigned short (&xb)[50][136], unsigned short (&ht)[128][72],
    float* __restrict__ f1s, float* __restrict__ f2s, int w, int lane) {
    const int n = lane & 15, quad = lane >> 4;
    const int mrd = w * 16 + n;
    const int mr = (mrd < 50) ? mrd : 49;
    f32x4 acc[9];
#pragma unroll
    for (int nt = 0; nt < 9; ++nt) acc[nt] = (f32x4){0.f, 0.f, 0.f, 0.f};

#pragma unroll
    for (int kt = 0; kt < 4; ++kt) {
        const bf16x8 af = *(const bf16x8*)&xb[mr][kt * 32 + quad * 8];
        const unsigned short* bp = Wb + (((kt * 9) * 64 + lane) << 3);
#pragma unroll
        for (int nt = 0; nt < 9; ++nt) {
            const bf16x8 bfr = *(const bf16x8*)(bp + (nt << 9));
            acc[nt] = __builtin_amdgcn_mfma_f32_16x16x32_bf16(af, bfr, acc[nt], 0, 0, 0);
        }
    }
    // C/D: col = lane&15 (+16*nt), row = w*16 + quad*4 + reg -> ht[col][row]
    const int rbase = w * 16 + quad * 4;
#pragma unroll
    for (int nt = 0; nt < 8; ++nt) {
        const int col = nt * 16 + n;
        ushort4 pk;
        pk.x = f2bfu(acc[nt][0]);
        pk.y = f2bfu(acc[nt][1]);
        pk.z = f2bfu(acc[nt][2]);
        pk.w = f2bfu(acc[nt][3]);
        *(ushort4*)&ht[col][rbase] = pk;  // 8B aligned (144B row stride)
    }
    if (n < 2) {
        float* fs = n ? f2s : f1s;  // fsc[128]: junk rows 50..63 land in-bounds
#pragma unroll
        for (int reg = 0; reg < 4; ++reg) fs[rbase + reg] = acc[8][reg];
    }
}

// ---------------- fused m1 + m2 + H-softmax ---------------------------------
// m1 = tanh(x @ att1_W + att1_b) stays in registers; m2 = m1 @ att2_W + att2_b
// accumulated per-lane, reduced over the 16 lanes of a quad (xor 1,2,4,8),
// softmaxed over H=4 and written straight to attn4.
__device__ __forceinline__ void gemm_m1_m2(
    const unsigned short* __restrict__ Wb, const float* __restrict__ att1_b,
    const float* __restrict__ att2_W, const float* __restrict__ att2_b,
    const unsigned short (&xb)[50][136], float* __restrict__ attn4,
    int w, int lane) {
    const int n = lane & 15, quad = lane >> 4;
    const int mrd = w * 16 + n;
    const int mr = (mrd < 50) ? mrd : 49;
    f32x4 acc[8];
#pragma unroll
    for (int nt = 0; nt < 8; ++nt) acc[nt] = (f32x4){0.f, 0.f, 0.f, 0.f};

#pragma unroll
    for (int kt = 0; kt < 4; ++kt) {
        const bf16x8 af = *(const bf16x8*)&xb[mr][kt * 32 + quad * 8];
        const unsigned short* bp = Wb + (((kt * 8) * 64 + lane) << 3);
#pragma unroll
        for (int nt = 0; nt < 8; ++nt) {
            const bf16x8 bfr = *(const bf16x8*)(bp + (nt << 9));
            acc[nt] = __builtin_amdgcn_mfma_f32_16x16x32_bf16(af, bfr, acc[nt], 0, 0, 0);
        }
    }

    float pm[4][4];  // [reg][h] partial m2, static-indexed (stays in VGPRs)
#pragma unroll
    for (int r = 0; r < 4; ++r)
#pragma unroll
        for (int h = 0; h < 4; ++h) pm[r][h] = 0.f;

#pragma unroll
    for (int nt = 0; nt < 8; ++nt) {
        const int col = nt * 16 + n;
        const float bv = att1_b[col];                       // L1-hot
        const float4 a4 = *(const float4*)&att2_W[col * 4]; // L1-hot
#pragma unroll
        for (int r = 0; r < 4; ++r) {
            const float tv = tanh_fast(acc[nt][r] + bv);
            pm[r][0] = fmaf(tv, a4.x, pm[r][0]);
            pm[r][1] = fmaf(tv, a4.y, pm[r][1]);
            pm[r][2] = fmaf(tv, a4.z, pm[r][2]);
            pm[r][3] = fmaf(tv, a4.w, pm[r][3]);
        }
    }
    // reduce across the 16 lanes of this quad (cols n,16+n,...,112+n cover all 128)
#pragma unroll
    for (int r = 0; r < 4; ++r)
#pragma unroll
        for (int h = 0; h < 4; ++h) {
            float v = pm[r][h];
            v += __shfl_xor(v, 1, 64);
            v += __shfl_xor(v, 2, 64);
            v += __shfl_xor(v, 4, 64);
            v += __shfl_xor(v, 8, 64);
            pm[r][h] = v;
        }
    if (n == 0) {
        const float ab0 = att2_b[0], ab1 = att2_b[1], ab2 = att2_b[2], ab3 = att2_b[3];
        const int rbase = w * 16 + quad * 4;
#pragma unroll
        for (int r = 0; r < 4; ++r) {
            const int row = rbase + r;
            if (row < L_) {
                const float m0 = pm[r][0] + ab0, m1 = pm[r][1] + ab1;
                const float m2 = pm[r][2] + ab2, m3 = pm[r][3] + ab3;
                const float mx = fmaxf(fmaxf(m0, m1), fmaxf(m2, m3));
                const float e0 = __expf(m0 - mx), e1 = __expf(m1 - mx);
                const float e2 = __expf(m2 - mx), e3 = __expf(m3 - mx);
                const float inv = 1.f / (e0 + e1 + e2 + e3);
                *(float4*)&attn4[row * 4] =
                    make_float4(e0 * inv, e1 * inv, e2 * inv, e3 * inv);
            }
        }
    }
}

extern "C" __global__ void __launch_bounds__(256, 4) magnn_fused(
    const int* __restrict__ iseq, const int* __restrict__ uids,
    const int* __restrict__ itp, const int* __restrict__ A,
    const float* __restrict__ item_emb, const float* __restrict__ user_emb,
    const float* __restrict__ W2t, const float* __restrict__ b2t,
    const float* __restrict__ att1_b, const float* __restrict__ att2_W,
    const float* __restrict__ att2_b, const float* __restrict__ user_com,
    const unsigned short* __restrict__ Wb, float* __restrict__ out) {
    // LDS: xb 13600 + ht 18432 + Pb 7200 + fsc 512 = 39744 B -> 4 blocks/CU.
    // Strides 136/72 ushorts (272/144 B): 16B-aligned b128 frags, <=2-way banks.
    __shared__ __align__(16) unsigned short xb[50][136];  // x, bf16 row-major
    __shared__ __align__(16) unsigned short ht[128][72];  // h^T, bf16 col-major
    __shared__ __align__(16) unsigned short Pb[50][72];   // E (unnorm attn), bf16
    __shared__ __align__(16) float fsc[128];
    float* f1s = fsc;
    float* f2s = fsc + 64;
    float* S = (float*)&Pb[0][0];  // Pb dead after GAT layers:
    float* attn4 = S;              // [200] 50 x float4
    float* cat = S + 256;          // [256]
    float* fpart = S + 512;        // [128]
    float* vvec = S + 640;         // [128]
    float* zpart = S + 768;        // [4][128]

    const int tid = threadIdx.x;
    const int b = blockIdx.x;
    const int w = tid >> 6, lane = tid & 63;
    const int n16 = lane & 15, quad = lane >> 4;

    // ---- preload A rows as 13-bit mask (layer-invariant, round-robin rows) ----
    const int* Ab = A + (size_t)b * (L_ * L_);
    unsigned amask = 0;
    if (lane < L_) {
#pragma unroll
        for (int k = 0; k < 13; ++k) {
            const int l = w + 4 * k;
            if (l < L_) amask |= (Ab[l * L_ + lane] > 0) ? (1u << k) : 0u;
        }
    }

    // ---- gather item embeddings -> xb (bf16); sval exact fp32 from global ----
    const int* isq = iseq + b * L_;
    for (int i = tid; i < L_ * 32; i += 256) {
        const int l = i >> 5, c4 = (i & 31) << 2;
        const float4 v = *(const float4*)&item_emb[(size_t)isq[l] * 128 + c4];
        ushort4 pk;
        pk.x = f2bfu(v.x); pk.y = f2bfu(v.y); pk.z = f2bfu(v.z); pk.w = f2bfu(v.w);
        *(ushort4*)&xb[l][c4] = pk;
    }
    float sval = 0.f;
    if (tid < 128) {
#pragma unroll 10
        for (int l = 0; l < L_; ++l)
            sval += item_emb[(size_t)isq[l] * 128 + tid];  // L1/L2-hot re-read
    }
    __syncthreads();  // B0

    // ---- 2 GAT layers: 3 barriers each (proven-fast R2 schedule) ----
#pragma unroll 1
    for (int layer = 0; layer < 2; ++layer) {
        gemm50_gat(Wb + layer * 18432, xb, ht, f1s, f2s, w, lane);
        __syncthreads();  // B1: ht + f1/f2 visible to all waves
        // E = exp(tanh(f1+f2)) masked (bounded => no max shift; identical to
        // ref's max-subtracted softmax). Row-sum folded into PV (ones-col MFMA).
        {
            const float f2v = (lane < L_) ? f2s[lane] : 0.f;
#pragma unroll
            for (int k = 0; k < 13; ++k) {
                const int l = w + 4 * k;
                if (l < L_) {
                    const float e = tanh_fast(f1s[l] + f2v);
                    const float p = ((amask >> k) & 1u) ? __expf(e) : 0.f;
                    Pb[l][lane] = f2bfu(p);  // masked/junk lanes: exact 0
                }
            }
        }
        __syncthreads();  // B1b: Pb visible (rows written round-robin)
        // h' = (E @ h) * rcp(E @ 1) via MFMA; elu -> xb
        {
            const int pm = w * 16 + n16;
            const int pmc = (pm < 50) ? pm : 49;
            const bf16x8 pa0 = *(const bf16x8*)&Pb[pmc][quad * 8];
            const bf16x8 pa1 = *(const bf16x8*)&Pb[pmc][32 + quad * 8];
            // ones-column B-frag: col 0 = 1.0 for all k (E cols >=50 are 0)
            bf16x8 bones;
#pragma unroll
            for (int j = 0; j < 8; ++j)
                bones[j] = (n16 == 0) ? (short)0x3F80 : (short)0;
            f32x4 sacc = (f32x4){0.f, 0.f, 0.f, 0.f};
            sacc = __builtin_amdgcn_mfma_f32_16x16x32_bf16(pa0, bones, sacc, 0, 0, 0);
            sacc = __builtin_amdgcn_mfma_f32_16x16x32_bf16(pa1, bones, sacc, 0, 0, 0);
            f32x4 oacc[8];
#pragma unroll
            for (int nt = 0; nt < 8; ++nt) oacc[nt] = (f32x4){0.f, 0.f, 0.f, 0.f};
#pragma unroll
            for (int nt = 0; nt < 8; ++nt) {
                const bf16x8 h0 = *(const bf16x8*)&ht[nt * 16 + n16][quad * 8];
                oacc[nt] = __builtin_amdgcn_mfma_f32_16x16x32_bf16(pa0, h0, oacc[nt], 0, 0, 0);
            }
#pragma unroll
            for (int nt = 0; nt < 8; ++nt) {
                const bf16x8 h1 = *(const bf16x8*)&ht[nt * 16 + n16][32 + quad * 8];
                oacc[nt] = __builtin_amdgcn_mfma_f32_16x16x32_bf16(pa1, h1, oacc[nt], 0, 0, 0);
            }
            // row sums live in lane quad*16 (col 0), element reg; broadcast + rcp
            float rinv[4];
#pragma unroll
            for (int reg = 0; reg < 4; ++reg) {
                const float s = __shfl(sacc[reg], (lane & 48), 64);
                rinv[reg] = __builtin_amdgcn_rcpf(s);
            }
            const int rb = w * 16 + quad * 4;
            if (w < 3) {  // rows rb..rb+3 <= 47 < 50: no guards (wave-uniform)
#pragma unroll
                for (int nt = 0; nt < 8; ++nt) {
#pragma unroll
                    for (int reg = 0; reg < 4; ++reg) {
                        float e = oacc[nt][reg] * rinv[reg];
                        e = (e > 0.f) ? e : (__expf(e) - 1.f);
                        xb[rb + reg][nt * 16 + n16] = f2bfu(e);
                    }
                }
            } else {  // wave 3: only rows 48,49 valid
#pragma unroll
                for (int nt = 0; nt < 8; ++nt) {
#pragma unroll
                    for (int reg = 0; reg < 4; ++reg) {
                        const int row = rb + reg;
                        if (row < L_) {
                            float e = oacc[nt][reg] * rinv[reg];
                            e = (e > 0.f) ? e : (__expf(e) - 1.f);
                            xb[row][nt * 16 + n16] = f2bfu(e);
                        }
                    }
                }
            }
        }
        __syncthreads();  // B2: xb/ht handoff to next phase
    }

    // ---- m1+m2+softmax fused in registers -> attn4 (Pb region now dead) ----
    gemm_m1_m2(Wb + 36864, att1_b, att2_W, att2_b, xb, attn4, w, lane);
    __syncthreads();  // B3: attn4 visible

    // ---- prefetch out-phase indices/biases: latency hides under z + fusion ----
    const int* itpb = itp + b * T_;
    const int tq = w * 4 + quad;  // 0..15
    int ti[7];
    float bvp[7];
#pragma unroll
    for (int i = 0; i < 7; ++i) {
        const int t = i * 16 + tq;
        ti[i] = itpb[(t < T_) ? t : 0];
    }
#pragma unroll
    for (int i = 0; i < 7; ++i) bvp[i] = b2t[ti[i]];

    // ---- matrix_z with all 256 threads: halves of L, partials via LDS ----
    {
        const int d = tid & 127, hf2 = tid >> 7;
        float z0 = 0.f, z1 = 0.f, z2 = 0.f, z3 = 0.f;
        const int l0 = hf2 * 25;
#pragma unroll
        for (int li = 0; li < 25; ++li) {
            const int l = l0 + li;
            const float xv = bf2f(xb[l][d]);
            const float4 at = *(const float4*)&attn4[l * 4];  // broadcast
            z0 = fmaf(xv, at.x, z0);
            z1 = fmaf(xv, at.y, z1);
            z2 = fmaf(xv, at.z, z2);
            z3 = fmaf(xv, at.w, z3);
        }
        if (hf2) {
            zpart[0 * 128 + d] = z0;
            zpart[1 * 128 + d] = z1;
            zpart[2 * 128 + d] = z2;
            zpart[3 * 128 + d] = z3;
            cat[128 + d] = user_emb[(size_t)uids[b] * 128 + d];
        }
        __syncthreads();  // B4
        if (!hf2) {
            z0 += zpart[0 * 128 + d];
            z1 += zpart[1 * 128 + d];
            z2 += zpart[2 * 128 + d];
            z3 += zpart[3 * 128 + d];
            cat[d] = 0.25f * (tanh_fast(z0) + tanh_fast(z1) +
                              tanh_fast(z2) + tanh_fast(z3));
        }
        __syncthreads();  // B5
    }

    // ---- fusion = cat @ user_com (coalesced strided cols); v = fusion + s ----
    {
        const int g = tid & 127, hf = tid >> 7;
        const float* ucb = user_com + hf * 128 * 128 + g;
        const float* cc = cat + hf * 128;
        float acc = 0.f;
#pragma unroll 16
        for (int k = 0; k < 128; ++k) acc = fmaf(cc[k], ucb[(size_t)k * 128], acc);
        if (hf) fpart[g] = acc;
        __syncthreads();  // B6
        if (!hf) vvec[g] = acc + fpart[g] + sval;
    }
    __syncthreads();  // B7

    // ---- out[b,t] = w2[t]·v + b2[t]; one t per 16-lane quad group ----
    // lane n16 holds v[n16*8..n16*8+7]; reduction = 4 intra-quad shuffles.
    {
        const float4 vva = *(const float4*)&vvec[n16 * 8];
        const float4 vvb = *(const float4*)&vvec[n16 * 8 + 4];
#pragma unroll
        for (int i = 0; i < 7; ++i) {
            const int t = i * 16 + tq;
            const float* wr = W2t + (size_t)ti[i] * 128 + n16 * 8;
            const float4 wa = *(const float4*)wr;
            const float4 wb = *(const float4*)(wr + 4);
            float r = wa.x * vva.x;
            r = fmaf(wa.y, vva.y, r);
            r = fmaf(wa.z, vva.z, r);
            r = fmaf(wa.w, vva.w, r);
            r = fmaf(wb.x, vvb.x, r);
            r = fmaf(wb.y, vvb.y, r);
            r = fmaf(wb.z, vvb.z, r);
            r = fmaf(wb.w, vvb.w, r);
            r += __shfl_xor(r, 1, 64);
            r += __shfl_xor(r, 2, 64);
            r += __shfl_xor(r, 4, 64);
            r += __shfl_xor(r, 8, 64);
            if (n16 == 0 && t < T_) out[b * T_ + t] = r + bvp[i];
        }
    }
}

extern "C" void kernel_launch(void* const* d_in, const int* in_sizes, int n_in,
                              void* d_out, int out_size, void* d_ws, size_t ws_size,
                              hipStream_t stream) {
    const int* iseq = (const int*)d_in[0];
    const int* uids = (const int*)d_in[1];
    const int* itp = (const int*)d_in[2];
    const int* A = (const int*)d_in[3];
    const float* item_emb = (const float*)d_in[4];
    const float* user_emb = (const float*)d_in[5];
    const float* W2t = (const float*)d_in[6];
    const float* b2t = (const float*)d_in[7];
    const float* W_att = (const float*)d_in[8];
    const float* a_att = (const float*)d_in[9];
    const float* W_out = (const float*)d_in[10];
    const float* a_out = (const float*)d_in[11];
    const float* att1_W = (const float*)d_in[12];
    const float* att1_b = (const float*)d_in[13];
    const float* att2_W = (const float*)d_in[14];
    const float* att2_b = (const float*)d_in[15];
    const float* user_com = (const float*)d_in[16];
    float* out = (float*)d_out;
    unsigned short* Wb = (unsigned short*)d_ws;  // 53248 bf16 = 104 KiB

    magnn_preswizzle<<<dim3(26), dim3(256), 0, stream>>>(W_att, W_out, att1_W,
                                                         a_att, a_out, Wb);

    const int B = in_sizes[1];  // user_ids is (B,)
    magnn_fused<<<dim3(B), dim3(256), 0, stream>>>(
        iseq, uids, itp, A, item_emb, user_emb, W2t, b2t, att1_b, att2_W,
        att2_b, user_com, Wb, out);
}

// Round 6
// 344.176 us; speedup vs baseline: 1.3383x; 1.0015x over previous
//
#include <hip/hip_runtime.h>
#include <math.h>

#define L_  50
#define T_  100
#define NEG_INF_ -9000000000000000.0f

using bf16x8 = __attribute__((ext_vector_type(8))) short;
using f32x4 = __attribute__((ext_vector_type(4))) float;

__device__ __forceinline__ short f2bf(float f) {  // RNE fp32 -> bf16 bits
    unsigned u = __float_as_uint(f);
    return (short)((u + 0x7fffu + ((u >> 16) & 1u)) >> 16);
}
__device__ __forceinline__ unsigned short f2bfu(float f) {
    unsigned u = __float_as_uint(f);
    return (unsigned short)((u + 0x7fffu + ((u >> 16) & 1u)) >> 16);
}
__device__ __forceinline__ float bf2f(unsigned short u) {
    return __uint_as_float(((unsigned)u) << 16);
}
// tanh via exp+rcp: ~7 instr, |rel err| ~1e-7 (vs ~20-instr libm tanhf)
__device__ __forceinline__ float tanh_fast(float x) {
    const float cx = fminf(fmaxf(x, -15.f), 15.f);
    const float t = __expf(2.f * cx);
    return (t - 1.f) * __builtin_amdgcn_rcpf(t + 1.f);
}

// ---------------- pre-pass: W -> bf16 MFMA B-frags ---------------------------
// 104 blocks x 64 lanes (1 group per block: minimizes serial pre-pass latency).
// mats 0,1 (W_att, W_out): 9 N-tiles; tile 8 = [W@a1 | W@a2 | 0...] (f1/f2 fold).
// mat 2 (att1_W): 8 N-tiles.
// B-frag of mfma_f32_16x16x32_bf16: lane holds B[k = (lane>>4)*8 + j][n = lane&15].
extern "C" __global__ void __launch_bounds__(64) magnn_preswizzle(
    const float* __restrict__ W0, const float* __restrict__ W1,
    const float* __restrict__ W2, const float* __restrict__ a0,
    const float* __restrict__ a1v, unsigned short* __restrict__ out) {
    const int gid = blockIdx.x, lane = threadIdx.x;
    int mat, kt, nt;
    size_t base;
    if (gid < 72) {
        mat = gid / 36;
        const int rem = gid % 36;
        kt = rem / 9;
        nt = rem % 9;
        base = (size_t)mat * 18432 + (size_t)(((kt * 9 + nt) * 64 + lane) << 3);
    } else {
        mat = 2;
        const int rem = gid - 72;
        kt = rem >> 3;
        nt = rem & 7;
        base = 36864 + (size_t)(((kt * 8 + nt) * 64 + lane) << 3);
    }
    const float* Ws = (mat == 0) ? W0 : (mat == 1) ? W1 : W2;
    const int n = lane & 15;
    const int k0 = kt * 32 + (lane >> 4) * 8;
    bf16x8 v;
    if (nt < 8) {
        const int col = nt * 16 + n;
#pragma unroll
        for (int j = 0; j < 8; ++j) v[j] = f2bf(Ws[(size_t)(k0 + j) * 128 + col]);
    } else {
        // fold tile: 16 (j,vec) dots of len 128, parallel over 16 lanes of quad
        const float* avb = (mat == 0) ? a0 : a1v;
#pragma unroll
        for (int j = 0; j < 8; ++j) v[j] = 0;
#pragma unroll
        for (int pv = 0; pv < 16; ++pv) {
            const int j = pv & 7, vec = pv >> 3;
            const float* wr = Ws + (size_t)(k0 + j) * 128 + n * 8;
            const float* av = avb + vec * 128 + n * 8;
            float s = 0.f;
#pragma unroll
            for (int g = 0; g < 8; ++g) s = fmaf(wr[g], av[g], s);
            s += __shfl_xor(s, 1, 16);
            s += __shfl_xor(s, 2, 16);
            s += __shfl_xor(s, 4, 16);
            s += __shfl_xor(s, 8, 16);
            if (n == vec) v[j] = f2bf(s);
        }
    }
    *(bf16x8*)(out + base) = v;
}

// ---------------- MFMA gemm (GAT): ht^T = xb(50x128 bf16) @ W, + f1/f2 fold --
// Wave w owns output rows w*16..w*16+15 (rows>=50 computed from clamped row 49,
// stored as finite junk into ht rows 50..63 -- harmless, multiplied by P=0).
// ht layout: ht[col][row] (col-major) so P@h B-frags are contiguous.
__device__ __forceinline__ void gemm50_gat(
    const unsigned short* __restrict__ Wb,
    const unsigned short (&xb)[50][136], unsigned short (&ht)[128][72],
    float* __restrict__ f1s, float* __restrict__ f2s, int w, int lane) {
    const int n = lane & 15, quad = lane >> 4;
    const int mrd = w * 16 + n;
    const int mr = (mrd < 50) ? mrd : 49;
    f32x4 acc[9];
#pragma unroll
    for (int nt = 0; nt < 9; ++nt) acc[nt] = (f32x4){0.f, 0.f, 0.f, 0.f};

#pragma unroll
    for (int kt = 0; kt < 4; ++kt) {
        const bf16x8 af = *(const bf16x8*)&xb[mr][kt * 32 + quad * 8];
        const unsigned short* bp = Wb + (((kt * 9) * 64 + lane) << 3);
#pragma unroll
        for (int nt = 0; nt < 9; ++nt) {
            const bf16x8 bfr = *(const bf16x8*)(bp + (nt << 9));
            acc[nt] = __builtin_amdgcn_mfma_f32_16x16x32_bf16(af, bfr, acc[nt], 0, 0, 0);
        }
    }
    // C/D: col = lane&15 (+16*nt), row = w*16 + quad*4 + reg -> ht[col][row]
    const int rbase = w * 16 + quad * 4;
#pragma unroll
    for (int nt = 0; nt < 8; ++nt) {
        const int col = nt * 16 + n;
        ushort4 pk;
        pk.x = f2bfu(acc[nt][0]);
        pk.y = f2bfu(acc[nt][1]);
        pk.z = f2bfu(acc[nt][2]);
        pk.w = f2bfu(acc[nt][3]);
        *(ushort4*)&ht[col][rbase] = pk;  // 8B aligned (144B row stride)
    }
    if (n < 2) {
        float* fs = n ? f2s : f1s;  // fsc[128]: junk rows 50..63 land in-bounds
#pragma unroll
        for (int reg = 0; reg < 4; ++reg) fs[rbase + reg] = acc[8][reg];
    }
}

// ---------------- fused m1 + m2 + H-softmax ---------------------------------
// m1 = tanh(x @ att1_W + att1_b) stays in registers; m2 = m1 @ att2_W + att2_b
// accumulated per-lane, reduced over the 16 lanes of a quad (xor 1,2,4,8),
// softmaxed over H=4 and written straight to attn4.
__device__ __forceinline__ void gemm_m1_m2(
    const unsigned short* __restrict__ Wb, const float* __restrict__ att1_b,
    const float* __restrict__ att2_W, const float* __restrict__ att2_b,
    const unsigned short (&xb)[50][136], float* __restrict__ attn4,
    int w, int lane) {
    const int n = lane & 15, quad = lane >> 4;
    const int mrd = w * 16 + n;
    const int mr = (mrd < 50) ? mrd : 49;
    f32x4 acc[8];
#pragma unroll
    for (int nt = 0; nt < 8; ++nt) acc[nt] = (f32x4){0.f, 0.f, 0.f, 0.f};

#pragma unroll
    for (int kt = 0; kt < 4; ++kt) {
        const bf16x8 af = *(const bf16x8*)&xb[mr][kt * 32 + quad * 8];
        const unsigned short* bp = Wb + (((kt * 8) * 64 + lane) << 3);
#pragma unroll
        for (int nt = 0; nt < 8; ++nt) {
            const bf16x8 bfr = *(const bf16x8*)(bp + (nt << 9));
            acc[nt] = __builtin_amdgcn_mfma_f32_16x16x32_bf16(af, bfr, acc[nt], 0, 0, 0);
        }
    }

    float pm[4][4];  // [reg][h] partial m2, static-indexed (stays in VGPRs)
#pragma unroll
    for (int r = 0; r < 4; ++r)
#pragma unroll
        for (int h = 0; h < 4; ++h) pm[r][h] = 0.f;

#pragma unroll
    for (int nt = 0; nt < 8; ++nt) {
        const int col = nt * 16 + n;
        const float bv = att1_b[col];                       // L1-hot
        const float4 a4 = *(const float4*)&att2_W[col * 4]; // L1-hot
#pragma unroll
        for (int r = 0; r < 4; ++r) {
            const float tv = tanh_fast(acc[nt][r] + bv);
            pm[r][0] = fmaf(tv, a4.x, pm[r][0]);
            pm[r][1] = fmaf(tv, a4.y, pm[r][1]);
            pm[r][2] = fmaf(tv, a4.z, pm[r][2]);
            pm[r][3] = fmaf(tv, a4.w, pm[r][3]);
        }
    }
    // reduce across the 16 lanes of this quad (cols n,16+n,...,112+n cover all 128)
#pragma unroll
    for (int r = 0; r < 4; ++r)
#pragma unroll
        for (int h = 0; h < 4; ++h) {
            float v = pm[r][h];
            v += __shfl_xor(v, 1, 64);
            v += __shfl_xor(v, 2, 64);
            v += __shfl_xor(v, 4, 64);
            v += __shfl_xor(v, 8, 64);
            pm[r][h] = v;
        }
    if (n == 0) {
        const float ab0 = att2_b[0], ab1 = att2_b[1], ab2 = att2_b[2], ab3 = att2_b[3];
        const int rbase = w * 16 + quad * 4;
#pragma unroll
        for (int r = 0; r < 4; ++r) {
            const int row = rbase + r;
            if (row < L_) {
                const float m0 = pm[r][0] + ab0, m1 = pm[r][1] + ab1;
                const float m2 = pm[r][2] + ab2, m3 = pm[r][3] + ab3;
                const float mx = fmaxf(fmaxf(m0, m1), fmaxf(m2, m3));
                const float e0 = __expf(m0 - mx), e1 = __expf(m1 - mx);
                const float e2 = __expf(m2 - mx), e3 = __expf(m3 - mx);
                const float inv = 1.f / (e0 + e1 + e2 + e3);
                *(float4*)&attn4[row * 4] =
                    make_float4(e0 * inv, e1 * inv, e2 * inv, e3 * inv);
            }
        }
    }
}

extern "C" __global__ void __launch_bounds__(256, 4) magnn_fused(
    const int* __restrict__ iseq, const int* __restrict__ uids,
    const int* __restrict__ itp, const int* __restrict__ A,
    const float* __restrict__ item_emb, const float* __restrict__ user_emb,
    const float* __restrict__ W2t, const float* __restrict__ b2t,
    const float* __restrict__ att1_b, const float* __restrict__ att2_W,
    const float* __restrict__ att2_b, const float* __restrict__ user_com,
    const unsigned short* __restrict__ Wb, float* __restrict__ out) {
    // LDS: xb 13600 + ht 18432 + Pb 7200 + fsc 512 = 39744 B -> 4 blocks/CU.
    // Strides 136/72 ushorts (272/144 B): 16B-aligned b128 frags; the stride-144
    // b128 access pattern is exactly 8 lanes per 4-bank group = minimum 8 passes
    // (SQ_LDS_BANK_CONFLICT ~4.29M is inherent wide-op multi-pass, not a lever).
    __shared__ __align__(16) unsigned short xb[50][136];  // x, bf16 row-major
    __shared__ __align__(16) unsigned short ht[128][72];  // h^T, bf16 col-major
    __shared__ __align__(16) unsigned short Pb[50][72];   // E (unnorm attn), bf16
    __shared__ __align__(16) float fsc[128];
    float* f1s = fsc;
    float* f2s = fsc + 64;
    float* S = (float*)&Pb[0][0];  // Pb dead after GAT layers:
    float* attn4 = S;              // [200] 50 x float4
    float* cat = S + 256;          // [256]
    float* fpart = S + 512;        // [128]
    float* vvec = S + 640;         // [128]
    float* zpart = S + 768;        // [4][128]

    const int tid = threadIdx.x;
    const int b = blockIdx.x;
    const int w = tid >> 6, lane = tid & 63;
    const int n16 = lane & 15, quad = lane >> 4;

    // ---- early-issue user_emb (independent; consumed in z-phase post-B4) ----
    float uemb = 0.f;
    if (tid >= 128) uemb = user_emb[(size_t)uids[b] * 128 + (tid - 128)];

    // ---- preload A rows as 13-bit mask (layer-invariant, round-robin rows) ----
    const int* Ab = A + (size_t)b * (L_ * L_);
    unsigned amask = 0;
    if (lane < L_) {
#pragma unroll
        for (int k = 0; k < 13; ++k) {
            const int l = w + 4 * k;
            if (l < L_) amask |= (Ab[l * L_ + lane] > 0) ? (1u << k) : 0u;
        }
    }

    // ---- gather item embeddings -> xb (bf16); sval exact fp32 from global ----
    const int* isq = iseq + b * L_;
    for (int i = tid; i < L_ * 32; i += 256) {
        const int l = i >> 5, c4 = (i & 31) << 2;
        const float4 v = *(const float4*)&item_emb[(size_t)isq[l] * 128 + c4];
        ushort4 pk;
        pk.x = f2bfu(v.x); pk.y = f2bfu(v.y); pk.z = f2bfu(v.z); pk.w = f2bfu(v.w);
        *(ushort4*)&xb[l][c4] = pk;
    }
    float sval = 0.f;
    if (tid < 128) {
#pragma unroll 10
        for (int l = 0; l < L_; ++l)
            sval += item_emb[(size_t)isq[l] * 128 + tid];  // L1/L2-hot re-read
    }
    __syncthreads();  // B0

    // ---- 2 GAT layers: 3 barriers each (proven-fast R2 schedule) ----
#pragma unroll 1
    for (int layer = 0; layer < 2; ++layer) {
        gemm50_gat(Wb + layer * 18432, xb, ht, f1s, f2s, w, lane);
        __syncthreads();  // B1: ht + f1/f2 visible to all waves
        // E = exp(tanh(f1+f2)) masked (bounded => no max shift; identical to
        // ref's max-subtracted softmax). Row-sum folded into PV (ones-col MFMA).
        {
            const float f2v = (lane < L_) ? f2s[lane] : 0.f;
#pragma unroll
            for (int k = 0; k < 13; ++k) {
                const int l = w + 4 * k;
                if (l < L_) {
                    const float e = tanh_fast(f1s[l] + f2v);
                    const float p = ((amask >> k) & 1u) ? __expf(e) : 0.f;
                    Pb[l][lane] = f2bfu(p);  // masked/junk lanes: exact 0
                }
            }
        }
        __syncthreads();  // B1b: Pb visible (rows written round-robin)
        // h' = (E @ h) * rcp(E @ 1) via MFMA; elu -> xb
        {
            const int pm = w * 16 + n16;
            const int pmc = (pm < 50) ? pm : 49;
            const bf16x8 pa0 = *(const bf16x8*)&Pb[pmc][quad * 8];
            const bf16x8 pa1 = *(const bf16x8*)&Pb[pmc][32 + quad * 8];
            // ones-column B-frag: col 0 = 1.0 for all k (E cols >=50 are 0)
            bf16x8 bones;
#pragma unroll
            for (int j = 0; j < 8; ++j)
                bones[j] = (n16 == 0) ? (short)0x3F80 : (short)0;
            f32x4 sacc = (f32x4){0.f, 0.f, 0.f, 0.f};
            sacc = __builtin_amdgcn_mfma_f32_16x16x32_bf16(pa0, bones, sacc, 0, 0, 0);
            sacc = __builtin_amdgcn_mfma_f32_16x16x32_bf16(pa1, bones, sacc, 0, 0, 0);
            f32x4 oacc[8];
#pragma unroll
            for (int nt = 0; nt < 8; ++nt) oacc[nt] = (f32x4){0.f, 0.f, 0.f, 0.f};
#pragma unroll
            for (int nt = 0; nt < 8; ++nt) {
                const bf16x8 h0 = *(const bf16x8*)&ht[nt * 16 + n16][quad * 8];
                oacc[nt] = __builtin_amdgcn_mfma_f32_16x16x32_bf16(pa0, h0, oacc[nt], 0, 0, 0);
            }
#pragma unroll
            for (int nt = 0; nt < 8; ++nt) {
                const bf16x8 h1 = *(const bf16x8*)&ht[nt * 16 + n16][32 + quad * 8];
                oacc[nt] = __builtin_amdgcn_mfma_f32_16x16x32_bf16(pa1, h1, oacc[nt], 0, 0, 0);
            }
            // row sums live in lane quad*16 (col 0), element reg; broadcast + rcp
            float rinv[4];
#pragma unroll
            for (int reg = 0; reg < 4; ++reg) {
                const float s = __shfl(sacc[reg], (lane & 48), 64);
                rinv[reg] = __builtin_amdgcn_rcpf(s);
            }
            const int rb = w * 16 + quad * 4;
            if (w < 3) {  // rows rb..rb+3 <= 47 < 50: no guards (wave-uniform)
#pragma unroll
                for (int nt = 0; nt < 8; ++nt) {
#pragma unroll
                    for (int reg = 0; reg < 4; ++reg) {
                        float e = oacc[nt][reg] * rinv[reg];
                        e = (e > 0.f) ? e : (__expf(e) - 1.f);
                        xb[rb + reg][nt * 16 + n16] = f2bfu(e);
                    }
                }
            } else {  // wave 3: only rows 48,49 valid
#pragma unroll
                for (int nt = 0; nt < 8; ++nt) {
#pragma unroll
                    for (int reg = 0; reg < 4; ++reg) {
                        const int row = rb + reg;
                        if (row < L_) {
                            float e = oacc[nt][reg] * rinv[reg];
                            e = (e > 0.f) ? e : (__expf(e) - 1.f);
                            xb[row][nt * 16 + n16] = f2bfu(e);
                        }
                    }
                }
            }
        }
        __syncthreads();  // B2: xb/ht handoff to next phase
    }

    // ---- m1+m2+softmax fused in registers -> attn4 (Pb region now dead) ----
    gemm_m1_m2(Wb + 36864, att1_b, att2_W, att2_b, xb, attn4, w, lane);
    __syncthreads();  // B3: attn4 visible

    // ---- prefetch out-phase indices/biases AND W2t row halves: the ~1.1k-cy
    // itp->W2t dependent-load chain hides under matrix_z + fusion (~2k cy VALU).
    // Only the first float4 of each row is held (28 VGPR); the second is
    // same-cache-line -> L1-hot when re-loaded in the out loop.
    const int* itpb = itp + b * T_;
    const int tq = w * 4 + quad;  // 0..15
    int ti[7];
    float bvp[7];
    float4 wva[7];
#pragma unroll
    for (int i = 0; i < 7; ++i) {
        const int t = i * 16 + tq;
        ti[i] = itpb[(t < T_) ? t : 0];
    }
#pragma unroll
    for (int i = 0; i < 7; ++i) bvp[i] = b2t[ti[i]];
#pragma unroll
    for (int i = 0; i < 7; ++i)
        wva[i] = *(const float4*)(W2t + (size_t)ti[i] * 128 + n16 * 8);

    // ---- matrix_z with all 256 threads: halves of L, partials via LDS ----
    {
        const int d = tid & 127, hf2 = tid >> 7;
        float z0 = 0.f, z1 = 0.f, z2 = 0.f, z3 = 0.f;
        const int l0 = hf2 * 25;
#pragma unroll
        for (int li = 0; li < 25; ++li) {
            const int l = l0 + li;
            const float xv = bf2f(xb[l][d]);
            const float4 at = *(const float4*)&attn4[l * 4];  // broadcast
            z0 = fmaf(xv, at.x, z0);
            z1 = fmaf(xv, at.y, z1);
            z2 = fmaf(xv, at.z, z2);
            z3 = fmaf(xv, at.w, z3);
        }
        if (hf2) {
            zpart[0 * 128 + d] = z0;
            zpart[1 * 128 + d] = z1;
            zpart[2 * 128 + d] = z2;
            zpart[3 * 128 + d] = z3;
            cat[128 + d] = uemb;  // preloaded at kernel start
        }
        __syncthreads();  // B4
        if (!hf2) {
            z0 += zpart[0 * 128 + d];
            z1 += zpart[1 * 128 + d];
            z2 += zpart[2 * 128 + d];
            z3 += zpart[3 * 128 + d];
            cat[d] = 0.25f * (tanh_fast(z0) + tanh_fast(z1) +
                              tanh_fast(z2) + tanh_fast(z3));
        }
        __syncthreads();  // B5
    }

    // ---- fusion = cat @ user_com (coalesced strided cols); v = fusion + s ----
    {
        const int g = tid & 127, hf = tid >> 7;
        const float* ucb = user_com + hf * 128 * 128 + g;
        const float* cc = cat + hf * 128;
        float acc = 0.f;
#pragma unroll 16
        for (int k = 0; k < 128; ++k) acc = fmaf(cc[k], ucb[(size_t)k * 128], acc);
        if (hf) fpart[g] = acc;
        __syncthreads();  // B6
        if (!hf) vvec[g] = acc + fpart[g] + sval;
    }
    __syncthreads();  // B7

    // ---- out[b,t] = w2[t]·v + b2[t]; one t per 16-lane quad group ----
    // lane n16 holds v[n16*8..n16*8+7]; reduction = 4 intra-quad shuffles.
    {
        const float4 vva = *(const float4*)&vvec[n16 * 8];
        const float4 vvb = *(const float4*)&vvec[n16 * 8 + 4];
#pragma unroll
        for (int i = 0; i < 7; ++i) {
            const int t = i * 16 + tq;
            const float4 wa = wva[i];  // prefetched pre-z
            const float4 wb =
                *(const float4*)(W2t + (size_t)ti[i] * 128 + n16 * 8 + 4);  // L1-hot
            float r0 = wa.x * vva.x;
            float r1 = wa.y * vva.y;
            r0 = fmaf(wa.z, vva.z, r0);
            r1 = fmaf(wa.w, vva.w, r1);
            r0 = fmaf(wb.x, vvb.x, r0);
            r1 = fmaf(wb.y, vvb.y, r1);
            r0 = fmaf(wb.z, vvb.z, r0);
            r1 = fmaf(wb.w, vvb.w, r1);
            float r = r0 + r1;
            r += __shfl_xor(r, 1, 64);
            r += __shfl_xor(r, 2, 64);
            r += __shfl_xor(r, 4, 64);
            r += __shfl_xor(r, 8, 64);
            if (n16 == 0 && t < T_) out[b * T_ + t] = r + bvp[i];
        }
    }
}

extern "C" void kernel_launch(void* const* d_in, const int* in_sizes, int n_in,
                              void* d_out, int out_size, void* d_ws, size_t ws_size,
                              hipStream_t stream) {
    const int* iseq = (const int*)d_in[0];
    const int* uids = (const int*)d_in[1];
    const int* itp = (const int*)d_in[2];
    const int* A = (const int*)d_in[3];
    const float* item_emb = (const float*)d_in[4];
    const float* user_emb = (const float*)d_in[5];
    const float* W2t = (const float*)d_in[6];
    const float* b2t = (const float*)d_in[7];
    const float* W_att = (const float*)d_in[8];
    const float* a_att = (const float*)d_in[9];
    const float* W_out = (const float*)d_in[10];
    const float* a_out = (const float*)d_in[11];
    const float* att1_W = (const float*)d_in[12];
    const float* att1_b = (const float*)d_in[13];
    const float* att2_W = (const float*)d_in[14];
    const float* att2_b = (const float*)d_in[15];
    const float* user_com = (const float*)d_in[16];
    float* out = (float*)d_out;
    unsigned short* Wb = (unsigned short*)d_ws;  // 53248 bf16 = 104 KiB

    magnn_preswizzle<<<dim3(104), dim3(64), 0, stream>>>(W_att, W_out, att1_W,
                                                         a_att, a_out, Wb);

    const int B = in_sizes[1];  // user_ids is (B,)
    magnn_fused<<<dim3(B), dim3(256), 0, stream>>>(
        iseq, uids, itp, A, item_emb, user_emb, W2t, b2t, att1_b, att2_W,
        att2_b, user_com, Wb, out);
}

// Round 7
// 339.455 us; speedup vs baseline: 1.3569x; 1.0139x over previous
//
#include <hip/hip_runtime.h>
#include <math.h>

#define L_  50
#define T_  100
#define NEG_INF_ -9000000000000000.0f

using bf16x8 = __attribute__((ext_vector_type(8))) short;
using f32x4 = __attribute__((ext_vector_type(4))) float;

__device__ __forceinline__ short f2bf(float f) {  // RNE fp32 -> bf16 bits
    unsigned u = __float_as_uint(f);
    return (short)((u + 0x7fffu + ((u >> 16) & 1u)) >> 16);
}
__device__ __forceinline__ unsigned short f2bfu(float f) {
    unsigned u = __float_as_uint(f);
    return (unsigned short)((u + 0x7fffu + ((u >> 16) & 1u)) >> 16);
}
__device__ __forceinline__ float bf2f(unsigned short u) {
    return __uint_as_float(((unsigned)u) << 16);
}
// tanh via exp+rcp: ~7 instr, |rel err| ~1e-7 (vs ~20-instr libm tanhf)
__device__ __forceinline__ float tanh_fast(float x) {
    const float cx = fminf(fmaxf(x, -15.f), 15.f);
    const float t = __expf(2.f * cx);
    return (t - 1.f) * __builtin_amdgcn_rcpf(t + 1.f);
}

// ---------------- pre-pass: W -> bf16 MFMA B-frags ---------------------------
// 104 blocks x 64 lanes. mats 0,1 (W_att, W_out): 9 N-tiles; tile 8 =
// [W@a1 | W@a2 | 0...] (f1/f2 fold). mat 2 (att1_W): 8 N-tiles.
// B-frag of mfma_f32_16x16x32_bf16: lane holds B[k = (lane>>4)*8 + j][n = lane&15].
extern "C" __global__ void __launch_bounds__(64) magnn_preswizzle(
    const float* __restrict__ W0, const float* __restrict__ W1,
    const float* __restrict__ W2, const float* __restrict__ a0,
    const float* __restrict__ a1v, unsigned short* __restrict__ out) {
    const int gid = blockIdx.x, lane = threadIdx.x;
    int mat, kt, nt;
    size_t base;
    if (gid < 72) {
        mat = gid / 36;
        const int rem = gid % 36;
        kt = rem / 9;
        nt = rem % 9;
        base = (size_t)mat * 18432 + (size_t)(((kt * 9 + nt) * 64 + lane) << 3);
    } else {
        mat = 2;
        const int rem = gid - 72;
        kt = rem >> 3;
        nt = rem & 7;
        base = 36864 + (size_t)(((kt * 8 + nt) * 64 + lane) << 3);
    }
    const float* Ws = (mat == 0) ? W0 : (mat == 1) ? W1 : W2;
    const int n = lane & 15;
    const int k0 = kt * 32 + (lane >> 4) * 8;
    bf16x8 v;
    if (nt < 8) {
        const int col = nt * 16 + n;
#pragma unroll
        for (int j = 0; j < 8; ++j) v[j] = f2bf(Ws[(size_t)(k0 + j) * 128 + col]);
    } else {
        // fold tile: 16 (j,vec) dots of len 128, parallel over 16 lanes of quad
        const float* avb = (mat == 0) ? a0 : a1v;
#pragma unroll
        for (int j = 0; j < 8; ++j) v[j] = 0;
#pragma unroll
        for (int pv = 0; pv < 16; ++pv) {
            const int j = pv & 7, vec = pv >> 3;
            const float* wr = Ws + (size_t)(k0 + j) * 128 + n * 8;
            const float* av = avb + vec * 128 + n * 8;
            float s = 0.f;
#pragma unroll
            for (int g = 0; g < 8; ++g) s = fmaf(wr[g], av[g], s);
            s += __shfl_xor(s, 1, 16);
            s += __shfl_xor(s, 2, 16);
            s += __shfl_xor(s, 4, 16);
            s += __shfl_xor(s, 8, 16);
            if (n == vec) v[j] = f2bf(s);
        }
    }
    *(bf16x8*)(out + base) = v;
}

// ---------------- MFMA gemm (GAT), 8-wave: wave (mw,nh) does M-tile mw, N-half nh
// nh=0: N-tiles 0..3; nh=1: N-tiles 4..7 + fold tile 8 (f1/f2).
// Rows>=50 computed from clamped row 49 -> junk in ht rows 50..63 (P=0 kills it).
// ht layout: ht[col][row] (col-major) so P@h B-frags are contiguous.
__device__ __forceinline__ void gemm50_gat8(
    const unsigned short* __restrict__ Wb,
    const unsigned short (&xb)[50][136], unsigned short (&ht)[128][72],
    float* __restrict__ f1s, float* __restrict__ f2s, int mw, int nh, int lane) {
    const int n = lane & 15, quad = lane >> 4;
    const int mrd = mw * 16 + n;
    const int mr = (mrd < 50) ? mrd : 49;
    const int rbase = mw * 16 + quad * 4;
    if (nh == 0) {
        f32x4 acc[4];
#pragma unroll
        for (int j = 0; j < 4; ++j) acc[j] = (f32x4){0.f, 0.f, 0.f, 0.f};
#pragma unroll
        for (int kt = 0; kt < 4; ++kt) {
            const bf16x8 af = *(const bf16x8*)&xb[mr][kt * 32 + quad * 8];
            const unsigned short* bp = Wb + (((kt * 9) * 64 + lane) << 3);
#pragma unroll
            for (int j = 0; j < 4; ++j) {
                const bf16x8 bfr = *(const bf16x8*)(bp + (j << 9));
                acc[j] = __builtin_amdgcn_mfma_f32_16x16x32_bf16(af, bfr, acc[j], 0, 0, 0);
            }
        }
#pragma unroll
        for (int j = 0; j < 4; ++j) {
            ushort4 pk;
            pk.x = f2bfu(acc[j][0]); pk.y = f2bfu(acc[j][1]);
            pk.z = f2bfu(acc[j][2]); pk.w = f2bfu(acc[j][3]);
            *(ushort4*)&ht[j * 16 + n][rbase] = pk;  // 8B aligned
        }
    } else {
        f32x4 acc[5];
#pragma unroll
        for (int j = 0; j < 5; ++j) acc[j] = (f32x4){0.f, 0.f, 0.f, 0.f};
#pragma unroll
        for (int kt = 0; kt < 4; ++kt) {
            const bf16x8 af = *(const bf16x8*)&xb[mr][kt * 32 + quad * 8];
            const unsigned short* bp = Wb + (((kt * 9 + 4) * 64 + lane) << 3);
#pragma unroll
            for (int j = 0; j < 5; ++j) {
                const bf16x8 bfr = *(const bf16x8*)(bp + (j << 9));
                acc[j] = __builtin_amdgcn_mfma_f32_16x16x32_bf16(af, bfr, acc[j], 0, 0, 0);
            }
        }
#pragma unroll
        for (int j = 0; j < 4; ++j) {
            ushort4 pk;
            pk.x = f2bfu(acc[j][0]); pk.y = f2bfu(acc[j][1]);
            pk.z = f2bfu(acc[j][2]); pk.w = f2bfu(acc[j][3]);
            *(ushort4*)&ht[(4 + j) * 16 + n][rbase] = pk;
        }
        if (n < 2) {
            float* fs = n ? f2s : f1s;  // fsc[128]: junk rows 50..63 in-bounds
#pragma unroll
            for (int reg = 0; reg < 4; ++reg) fs[rbase + reg] = acc[4][reg];
        }
    }
}

extern "C" __global__ void __launch_bounds__(512, 8) magnn_fused(
    const int* __restrict__ iseq, const int* __restrict__ uids,
    const int* __restrict__ itp, const int* __restrict__ A,
    const float* __restrict__ item_emb, const float* __restrict__ user_emb,
    const float* __restrict__ W2t, const float* __restrict__ b2t,
    const float* __restrict__ att1_b, const float* __restrict__ att2_W,
    const float* __restrict__ att2_b, const float* __restrict__ user_com,
    const unsigned short* __restrict__ Wb, float* __restrict__ out) {
    // 8 waves (512 thr): wave w = (mw = w&3 [M-tile], nh = w>>2 [N-half]).
    // LDS: xb 13600 + ht 18432 + Pb 7200 + fsc 512 = 39744 B -> 4 blocks/CU
    // -> 32 waves/CU (occupancy ceiling). ht region reused as f32 scratch after
    // the last PV (pmbuf/zpart/fp4). SQ_LDS_BANK_CONFLICT ~4.3M is inherent
    // wide-op multi-pass on the stride-144 b128 pattern, not a lever.
    __shared__ __align__(16) unsigned short xb[50][136];  // x, bf16 row-major
    __shared__ __align__(16) unsigned short ht[128][72];  // h^T, bf16 col-major
    __shared__ __align__(16) unsigned short Pb[50][72];   // E (unnorm attn), bf16
    __shared__ __align__(16) float fsc[128];
    float* f1s = fsc;
    float* f2s = fsc + 64;
    float* S = (float*)&Pb[0][0];   // Pb dead after GAT layers:
    float* attn4 = S;               // [200] 50 x float4
    float* cat = S + 256;           // [256]
    float* vvec = S + 512;          // [128]
    float* H = (float*)&ht[0][0];   // ht dead after last PV: 4608 floats
    float* pmbuf = H;               // [512]  m2 partials: [nh][row<64][h]
    float* zpart = H + 512;         // [1536] z partials: [qp-1][h][d]
    float* fp4 = H + 2048;          // [512]  fusion partials: [p][g]

    const int tid = threadIdx.x;
    const int b = blockIdx.x;
    const int w = tid >> 6, lane = tid & 63;
    const int mw = w & 3, nh = w >> 2;
    const int n16 = lane & 15, quad = lane >> 4;

    // ---- early-issue user_emb (consumed in z-phase by these same threads) ----
    float uemb = 0.f;
    if (tid >= 128 && tid < 256) uemb = user_emb[(size_t)uids[b] * 128 + (tid - 128)];

    // ---- preload A rows as 7-bit mask; rows l = w + 8k (layer-invariant) ----
    const int* Ab = A + (size_t)b * (L_ * L_);
    unsigned amask = 0;
    if (lane < L_) {
#pragma unroll
        for (int k = 0; k < 7; ++k) {
            const int l = w + 8 * k;
            if (l < L_) amask |= (Ab[l * L_ + lane] > 0) ? (1u << k) : 0u;
        }
    }

    // ---- gather item embeddings -> xb (bf16); sval exact fp32 from global ----
    const int* isq = iseq + b * L_;
    for (int i = tid; i < L_ * 32; i += 512) {
        const int l = i >> 5, c4 = (i & 31) << 2;
        const float4 v = *(const float4*)&item_emb[(size_t)isq[l] * 128 + c4];
        ushort4 pk;
        pk.x = f2bfu(v.x); pk.y = f2bfu(v.y); pk.z = f2bfu(v.z); pk.w = f2bfu(v.w);
        *(ushort4*)&xb[l][c4] = pk;
    }
    float sval = 0.f;
    if (tid < 128) {
#pragma unroll 10
        for (int l = 0; l < L_; ++l)
            sval += item_emb[(size_t)isq[l] * 128 + tid];  // L1/L2-hot re-read
    }
    __syncthreads();  // B0

    // ---- 2 GAT layers ----
#pragma unroll 1
    for (int layer = 0; layer < 2; ++layer) {
        gemm50_gat8(Wb + layer * 18432, xb, ht, f1s, f2s, mw, nh, lane);
        __syncthreads();  // B1: ht + f1/f2 visible
        // E = exp(tanh(f1+f2)) masked (bounded => no max shift; identical to
        // ref's max-subtracted softmax). Row-sum folded into PV (ones-col MFMA).
        {
            const float f2v = (lane < L_) ? f2s[lane] : 0.f;
#pragma unroll
            for (int k = 0; k < 7; ++k) {
                const int l = w + 8 * k;
                if (l < L_) {
                    const float e = tanh_fast(f1s[l] + f2v);
                    const float p = ((amask >> k) & 1u) ? __expf(e) : 0.f;
                    Pb[l][lane] = f2bfu(p);  // masked/junk lanes: exact 0
                }
            }
        }
        __syncthreads();  // B1b: Pb visible
        // h' = (E @ h) * rcp(E @ 1); wave (mw,nh): rows mw*16.., h-tiles nh*4..
        {
            const int pm = mw * 16 + n16;
            const int pmc = (pm < 50) ? pm : 49;
            const bf16x8 pa0 = *(const bf16x8*)&Pb[pmc][quad * 8];
            const bf16x8 pa1 = *(const bf16x8*)&Pb[pmc][32 + quad * 8];
            bf16x8 bones;  // ones-column: col 0 = 1.0 (E cols >=50 are 0)
#pragma unroll
            for (int j = 0; j < 8; ++j)
                bones[j] = (n16 == 0) ? (short)0x3F80 : (short)0;
            f32x4 sacc = (f32x4){0.f, 0.f, 0.f, 0.f};  // redundant per nh: cheap
            sacc = __builtin_amdgcn_mfma_f32_16x16x32_bf16(pa0, bones, sacc, 0, 0, 0);
            sacc = __builtin_amdgcn_mfma_f32_16x16x32_bf16(pa1, bones, sacc, 0, 0, 0);
            f32x4 oacc[4];
#pragma unroll
            for (int j = 0; j < 4; ++j) oacc[j] = (f32x4){0.f, 0.f, 0.f, 0.f};
#pragma unroll
            for (int j = 0; j < 4; ++j) {
                const bf16x8 h0 = *(const bf16x8*)&ht[(nh * 4 + j) * 16 + n16][quad * 8];
                oacc[j] = __builtin_amdgcn_mfma_f32_16x16x32_bf16(pa0, h0, oacc[j], 0, 0, 0);
            }
#pragma unroll
            for (int j = 0; j < 4; ++j) {
                const bf16x8 h1 = *(const bf16x8*)&ht[(nh * 4 + j) * 16 + n16][32 + quad * 8];
                oacc[j] = __builtin_amdgcn_mfma_f32_16x16x32_bf16(pa1, h1, oacc[j], 0, 0, 0);
            }
            float rinv[4];
#pragma unroll
            for (int reg = 0; reg < 4; ++reg) {
                const float s = __shfl(sacc[reg], (lane & 48), 64);
                rinv[reg] = __builtin_amdgcn_rcpf(s);
            }
            const int rb = mw * 16 + quad * 4;
            if (mw < 3) {  // rows <= 47: no guards (wave-uniform branch)
#pragma unroll
                for (int j = 0; j < 4; ++j) {
#pragma unroll
                    for (int reg = 0; reg < 4; ++reg) {
                        float e = oacc[j][reg] * rinv[reg];
                        e = (e > 0.f) ? e : (__expf(e) - 1.f);
                        xb[rb + reg][(nh * 4 + j) * 16 + n16] = f2bfu(e);
                    }
                }
            } else {  // mw 3: only rows 48,49 valid
#pragma unroll
                for (int j = 0; j < 4; ++j) {
#pragma unroll
                    for (int reg = 0; reg < 4; ++reg) {
                        const int row = rb + reg;
                        if (row < L_) {
                            float e = oacc[j][reg] * rinv[reg];
                            e = (e > 0.f) ? e : (__expf(e) - 1.f);
                            xb[row][(nh * 4 + j) * 16 + n16] = f2bfu(e);
                        }
                    }
                }
            }
        }
        __syncthreads();  // B2 (after layer 1: ht region becomes scratch)
    }

    // ---- m1+m2 partials: wave (mw,nh) covers cols nh*64..nh*64+63 ----
    {
        const int mrd = mw * 16 + n16;
        const int mr = (mrd < 50) ? mrd : 49;
        f32x4 acc[4];
#pragma unroll
        for (int j = 0; j < 4; ++j) acc[j] = (f32x4){0.f, 0.f, 0.f, 0.f};
#pragma unroll
        for (int kt = 0; kt < 4; ++kt) {
            const bf16x8 af = *(const bf16x8*)&xb[mr][kt * 32 + quad * 8];
            const unsigned short* bp = Wb + 36864 + (((kt * 8 + nh * 4) * 64 + lane) << 3);
#pragma unroll
            for (int j = 0; j < 4; ++j) {
                const bf16x8 bfr = *(const bf16x8*)(bp + (j << 9));
                acc[j] = __builtin_amdgcn_mfma_f32_16x16x32_bf16(af, bfr, acc[j], 0, 0, 0);
            }
        }
        float pm[4][4];  // [reg][h], static-indexed
#pragma unroll
        for (int r = 0; r < 4; ++r)
#pragma unroll
            for (int h = 0; h < 4; ++h) pm[r][h] = 0.f;
#pragma unroll
        for (int j = 0; j < 4; ++j) {
            const int col = (nh * 4 + j) * 16 + n16;
            const float bv = att1_b[col];                        // L1-hot
            const float4 a4 = *(const float4*)&att2_W[col * 4];  // L1-hot
#pragma unroll
            for (int r = 0; r < 4; ++r) {
                const float tv = tanh_fast(acc[j][r] + bv);
                pm[r][0] = fmaf(tv, a4.x, pm[r][0]);
                pm[r][1] = fmaf(tv, a4.y, pm[r][1]);
                pm[r][2] = fmaf(tv, a4.z, pm[r][2]);
                pm[r][3] = fmaf(tv, a4.w, pm[r][3]);
            }
        }
#pragma unroll
        for (int r = 0; r < 4; ++r)
#pragma unroll
            for (int h = 0; h < 4; ++h) {
                float v = pm[r][h];
                v += __shfl_xor(v, 1, 64);
                v += __shfl_xor(v, 2, 64);
                v += __shfl_xor(v, 4, 64);
                v += __shfl_xor(v, 8, 64);
                pm[r][h] = v;
            }
        if (n16 == 0) {
            const int rbase = mw * 16 + quad * 4;
#pragma unroll
            for (int r = 0; r < 4; ++r)
#pragma unroll
                for (int h = 0; h < 4; ++h)
                    pmbuf[nh * 256 + (rbase + r) * 4 + h] = pm[r][h];
        }
    }
    __syncthreads();  // B3a: pmbuf visible

    // ---- combine m2 halves + H-softmax -> attn4 (one thread per row) ----
    if (tid < L_) {
        const float m0 = pmbuf[tid * 4 + 0] + pmbuf[256 + tid * 4 + 0] + att2_b[0];
        const float m1 = pmbuf[tid * 4 + 1] + pmbuf[256 + tid * 4 + 1] + att2_b[1];
        const float m2 = pmbuf[tid * 4 + 2] + pmbuf[256 + tid * 4 + 2] + att2_b[2];
        const float m3 = pmbuf[tid * 4 + 3] + pmbuf[256 + tid * 4 + 3] + att2_b[3];
        const float mx = fmaxf(fmaxf(m0, m1), fmaxf(m2, m3));
        const float e0 = __expf(m0 - mx), e1 = __expf(m1 - mx);
        const float e2 = __expf(m2 - mx), e3 = __expf(m3 - mx);
        const float inv = 1.f / (e0 + e1 + e2 + e3);
        *(float4*)&attn4[tid * 4] =
            make_float4(e0 * inv, e1 * inv, e2 * inv, e3 * inv);
    }
    // out-phase index/bias prefetch (no LDS; overlaps the tiny combine)
    const int* itpb = itp + b * T_;
    const int tq = tid >> 4;  // 0..31: one t per 16-lane group
    int ti[4];
    float bvp[4];
#pragma unroll
    for (int i = 0; i < 4; ++i) {
        const int t = i * 32 + tq;
        ti[i] = itpb[(t < T_) ? t : 0];
    }
#pragma unroll
    for (int i = 0; i < 4; ++i) bvp[i] = b2t[ti[i]];
    __syncthreads();  // B3: attn4 visible

    // ---- matrix_z: 4-way L-split (qp = wave-pair), partials via scratch ----
    {
        const int d = tid & 127, qp = tid >> 7;
        const int l0 = qp * 13, l1 = (l0 + 13 < L_) ? l0 + 13 : L_;
        float z0 = 0.f, z1 = 0.f, z2 = 0.f, z3 = 0.f;
        for (int l = l0; l < l1; ++l) {
            const float xv = bf2f(xb[l][d]);
            const float4 at = *(const float4*)&attn4[l * 4];  // broadcast
            z0 = fmaf(xv, at.x, z0);
            z1 = fmaf(xv, at.y, z1);
            z2 = fmaf(xv, at.z, z2);
            z3 = fmaf(xv, at.w, z3);
        }
        if (qp) {
            zpart[(qp - 1) * 512 + 0 * 128 + d] = z0;
            zpart[(qp - 1) * 512 + 1 * 128 + d] = z1;
            zpart[(qp - 1) * 512 + 2 * 128 + d] = z2;
            zpart[(qp - 1) * 512 + 3 * 128 + d] = z3;
        }
        if (qp == 1) cat[128 + d] = uemb;  // loaded at kernel start
        __syncthreads();  // B4
        if (!qp) {
#pragma unroll
            for (int q = 0; q < 3; ++q) {
                z0 += zpart[q * 512 + 0 * 128 + d];
                z1 += zpart[q * 512 + 1 * 128 + d];
                z2 += zpart[q * 512 + 2 * 128 + d];
                z3 += zpart[q * 512 + 3 * 128 + d];
            }
            cat[d] = 0.25f * (tanh_fast(z0) + tanh_fast(z1) +
                              tanh_fast(z2) + tanh_fast(z3));
        }
        __syncthreads();  // B5
    }

    // ---- fusion: 4-way K-split (coalesced strided cols); v = fusion + s ----
    {
        const int g = tid & 127, p = tid >> 7;
        const float* ucb = user_com + p * 64 * 128 + g;
        const float* cc = cat + p * 64;
        float acc = 0.f;
#pragma unroll 16
        for (int k = 0; k < 64; ++k) acc = fmaf(cc[k], ucb[(size_t)k * 128], acc);
        fp4[p * 128 + g] = acc;
        __syncthreads();  // B6
        if (tid < 128)
            vvec[tid] = fp4[tid] + fp4[128 + tid] + fp4[256 + tid] +
                        fp4[384 + tid] + sval;
    }
    __syncthreads();  // B7

    // ---- out[b,t] = w2[t]·v + b2[t]; one t per 16-lane group, 4 iters ----
    {
        const float4 vva = *(const float4*)&vvec[n16 * 8];
        const float4 vvb = *(const float4*)&vvec[n16 * 8 + 4];
#pragma unroll
        for (int i = 0; i < 4; ++i) {
            const int t = i * 32 + tq;
            const float* wr = W2t + (size_t)ti[i] * 128 + n16 * 8;
            const float4 wa = *(const float4*)wr;
            const float4 wb = *(const float4*)(wr + 4);
            float r0 = wa.x * vva.x;
            float r1 = wa.y * vva.y;
            r0 = fmaf(wa.z, vva.z, r0);
            r1 = fmaf(wa.w, vva.w, r1);
            r0 = fmaf(wb.x, vvb.x, r0);
            r1 = fmaf(wb.y, vvb.y, r1);
            r0 = fmaf(wb.z, vvb.z, r0);
            r1 = fmaf(wb.w, vvb.w, r1);
            float r = r0 + r1;
            r += __shfl_xor(r, 1, 64);
            r += __shfl_xor(r, 2, 64);
            r += __shfl_xor(r, 4, 64);
            r += __shfl_xor(r, 8, 64);
            if (n16 == 0 && t < T_) out[b * T_ + t] = r + bvp[i];
        }
    }
}

extern "C" void kernel_launch(void* const* d_in, const int* in_sizes, int n_in,
                              void* d_out, int out_size, void* d_ws, size_t ws_size,
                              hipStream_t stream) {
    const int* iseq = (const int*)d_in[0];
    const int* uids = (const int*)d_in[1];
    const int* itp = (const int*)d_in[2];
    const int* A = (const int*)d_in[3];
    const float* item_emb = (const float*)d_in[4];
    const float* user_emb = (const float*)d_in[5];
    const float* W2t = (const float*)d_in[6];
    const float* b2t = (const float*)d_in[7];
    const float* W_att = (const float*)d_in[8];
    const float* a_att = (const float*)d_in[9];
    const float* W_out = (const float*)d_in[10];
    const float* a_out = (const float*)d_in[11];
    const float* att1_W = (const float*)d_in[12];
    const float* att1_b = (const float*)d_in[13];
    const float* att2_W = (const float*)d_in[14];
    const float* att2_b = (const float*)d_in[15];
    const float* user_com = (const float*)d_in[16];
    float* out = (float*)d_out;
    unsigned short* Wb = (unsigned short*)d_ws;  // 53248 bf16 = 104 KiB

    magnn_preswizzle<<<dim3(104), dim3(64), 0, stream>>>(W_att, W_out, att1_W,
                                                         a_att, a_out, Wb);

    const int B = in_sizes[1];  // user_ids is (B,)
    magnn_fused<<<dim3(B), dim3(512), 0, stream>>>(
        iseq, uids, itp, A, item_emb, user_emb, W2t, b2t, att1_b, att2_W,
        att2_b, user_com, Wb, out);
}